// Round 2
// baseline (1060.723 us; speedup 1.0000x reference)
//
#include <hip/hip_runtime.h>
#include <math.h>

#define LEAKY 0.2f

__device__ __forceinline__ float leaky02(float z) { return z >= 0.f ? z : LEAKY * z; }

// ---------------- CSR build ----------------
__global__ void count_kernel(const int* __restrict__ ei, int* __restrict__ cnt, int E, int N) {
  int e = blockIdx.x * 256 + threadIdx.x;
  int EP = E + N;
  if (e >= EP) return;
  int d = (e < E) ? ei[E + e] : (e - E);
  atomicAdd(&cnt[d], 1);
}

// single-block scan: rowptr (exclusive, N+1) and cursor (= start offsets)
__global__ __launch_bounds__(1024) void scan_kernel(const int* __restrict__ cnt,
                                                    int* __restrict__ rowptr,
                                                    int* __restrict__ cursor, int n) {
  __shared__ int wsum[16];
  int tid = threadIdx.x;
  int lane = tid & 63, wv = tid >> 6;
  if (tid == 0) rowptr[0] = 0;
  int carry = 0;
  for (int base = 0; base < n; base += 1024) {
    int i = base + tid;
    int v = (i < n) ? cnt[i] : 0;
    int x = v;
#pragma unroll
    for (int off = 1; off < 64; off <<= 1) {
      int t = __shfl_up(x, off);
      if (lane >= off) x += t;
    }
    if (lane == 63) wsum[wv] = x;
    __syncthreads();
    if (wv == 0 && lane < 16) {
      int y = wsum[lane];
#pragma unroll
      for (int off = 1; off < 16; off <<= 1) {
        int t = __shfl_up(y, off);
        if (lane >= off) y += t;
      }
      wsum[lane] = y;
    }
    __syncthreads();
    int woff = (wv == 0) ? 0 : wsum[wv - 1];
    int incl = x + woff;
    if (i < n) {
      rowptr[i + 1] = carry + incl;
      cursor[i] = carry + incl - v;
    }
    int total = wsum[15];
    __syncthreads();
    carry += total;
  }
}

__global__ void fill_kernel(const int* __restrict__ ei, int* __restrict__ cursor,
                            int* __restrict__ srcs, int E, int N) {
  int e = blockIdx.x * 256 + threadIdx.x;
  int EP = E + N;
  if (e >= EP) return;
  int s, d;
  if (e < E) { s = ei[e]; d = ei[E + e]; } else { s = e - E; d = s; }
  int slot = atomicAdd(&cursor[d], 1);
  srcs[slot] = s;
}

// ---------------- fp32 GEMM: C[M,NC] = A[M,K] @ B[K,NC] ----------------
#define BM 128
#define BNT 128
#define BK 16
__global__ __launch_bounds__(256) void gemm_kernel(const float* __restrict__ A,
                                                   const float* __restrict__ B,
                                                   float* __restrict__ C, int M, int NC, int K) {
  __shared__ float As[BK][BM];
  __shared__ float Bs[BK][BNT];
  int tid = threadIdx.x;
  int bm = blockIdx.x * BM;
  int bn = blockIdx.y * BNT;
  int tx = tid & 15, ty = tid >> 4;
  float acc[8][8] = {};
  for (int k0 = 0; k0 < K; k0 += BK) {
#pragma unroll
    for (int l = 0; l < 2; ++l) {
      int idx = tid + l * 256;
      // A: 128 rows x 16 k  -> 512 float4
      int row = idx >> 2;
      int kq = (idx & 3) << 2;
      int gr = bm + row;
      float4 va = make_float4(0.f, 0.f, 0.f, 0.f);
      if (gr < M) va = *(const float4*)&A[(size_t)gr * K + k0 + kq];
      As[kq + 0][row] = va.x; As[kq + 1][row] = va.y;
      As[kq + 2][row] = va.z; As[kq + 3][row] = va.w;
      // B: 16 rows x 128 cols -> 512 float4
      int brow = idx >> 5;
      int bc = (idx & 31) << 2;
      float4 vb = *(const float4*)&B[(size_t)(k0 + brow) * NC + bn + bc];
      *(float4*)&Bs[brow][bc] = vb;
    }
    __syncthreads();
#pragma unroll
    for (int kk = 0; kk < BK; ++kk) {
      float4 a0 = *(const float4*)&As[kk][ty * 8];
      float4 a1 = *(const float4*)&As[kk][ty * 8 + 4];
      float4 b0 = *(const float4*)&Bs[kk][tx * 8];
      float4 b1 = *(const float4*)&Bs[kk][tx * 8 + 4];
      float av[8] = {a0.x, a0.y, a0.z, a0.w, a1.x, a1.y, a1.z, a1.w};
      float bv[8] = {b0.x, b0.y, b0.z, b0.w, b1.x, b1.y, b1.z, b1.w};
#pragma unroll
      for (int i = 0; i < 8; ++i)
#pragma unroll
        for (int j = 0; j < 8; ++j) acc[i][j] = fmaf(av[i], bv[j], acc[i][j]);
    }
    __syncthreads();
  }
#pragma unroll
  for (int i = 0; i < 8; ++i) {
    int gr = bm + ty * 8 + i;
    if (gr >= M) continue;
    float4 r0 = make_float4(acc[i][0], acc[i][1], acc[i][2], acc[i][3]);
    float4 r1 = make_float4(acc[i][4], acc[i][5], acc[i][6], acc[i][7]);
    *(float4*)&C[(size_t)gr * NC + bn + tx * 8] = r0;
    *(float4*)&C[(size_t)gr * NC + bn + tx * 8 + 4] = r1;
  }
}

// ---------------- attention dot: as/ad per (node, head) ----------------
__global__ __launch_bounds__(256) void attdot_kernel(const float* __restrict__ h,
                                                     const float* __restrict__ att_s,
                                                     const float* __restrict__ att_d,
                                                     float* __restrict__ as_, float* __restrict__ ad_) {
  int n = blockIdx.x;
  int tid = threadIdx.x;
  int head = tid >> 6, lane = tid & 63;
  float v = h[(size_t)n * 256 + tid];
  float ps = v * att_s[tid];
  float pd = v * att_d[tid];
#pragma unroll
  for (int off = 32; off > 0; off >>= 1) {
    ps += __shfl_down(ps, off);
    pd += __shfl_down(pd, off);
  }
  if (lane == 0) {
    as_[n * 4 + head] = ps;
    ad_[n * 4 + head] = pd;
  }
}

// ---------------- per-destination-node GAT aggregation ----------------
#define CHUNK 512
__global__ __launch_bounds__(256) void agg_kernel(const float* __restrict__ h,
                                                  const float* __restrict__ as_,
                                                  const float* __restrict__ ad_,
                                                  const int* __restrict__ rowptr,
                                                  const int* __restrict__ srcs,
                                                  const float* __restrict__ bias,
                                                  float* __restrict__ out) {
  int n = blockIdx.x;
  int tid = threadIdx.x;
  int e0 = rowptr[n], e1 = rowptr[n + 1];
  __shared__ float red[4][4];
  __shared__ float smax[4], sinv[4];
  __shared__ float wbuf[CHUNK * 4];
  __shared__ int sbuf[CHUNK];

  float4 adv = *(const float4*)&ad_[n * 4];
  float ad0 = adv.x, ad1 = adv.y, ad2 = adv.z, ad3 = adv.w;
  int wv = tid >> 6;

  // phase A: per-head max of leaky(as[src]+ad[dst])
  float mx0 = -1e30f, mx1 = -1e30f, mx2 = -1e30f, mx3 = -1e30f;
  for (int j = e0 + tid; j < e1; j += 256) {
    int s = srcs[j];
    float4 av = *(const float4*)&as_[s * 4];
    mx0 = fmaxf(mx0, leaky02(av.x + ad0));
    mx1 = fmaxf(mx1, leaky02(av.y + ad1));
    mx2 = fmaxf(mx2, leaky02(av.z + ad2));
    mx3 = fmaxf(mx3, leaky02(av.w + ad3));
  }
#pragma unroll
  for (int off = 32; off > 0; off >>= 1) {
    mx0 = fmaxf(mx0, __shfl_xor(mx0, off));
    mx1 = fmaxf(mx1, __shfl_xor(mx1, off));
    mx2 = fmaxf(mx2, __shfl_xor(mx2, off));
    mx3 = fmaxf(mx3, __shfl_xor(mx3, off));
  }
  if ((tid & 63) == 0) { red[wv][0] = mx0; red[wv][1] = mx1; red[wv][2] = mx2; red[wv][3] = mx3; }
  __syncthreads();
  if (tid < 4)
    smax[tid] = fmaxf(fmaxf(red[0][tid], red[1][tid]), fmaxf(red[2][tid], red[3][tid]));
  __syncthreads();
  float m0 = smax[0], m1 = smax[1], m2 = smax[2], m3 = smax[3];

  // phase B: per-head sum of exp(l - m)
  float s0 = 0.f, s1 = 0.f, s2 = 0.f, s3 = 0.f;
  for (int j = e0 + tid; j < e1; j += 256) {
    int s = srcs[j];
    float4 av = *(const float4*)&as_[s * 4];
    s0 += expf(leaky02(av.x + ad0) - m0);
    s1 += expf(leaky02(av.y + ad1) - m1);
    s2 += expf(leaky02(av.z + ad2) - m2);
    s3 += expf(leaky02(av.w + ad3) - m3);
  }
#pragma unroll
  for (int off = 32; off > 0; off >>= 1) {
    s0 += __shfl_xor(s0, off);
    s1 += __shfl_xor(s1, off);
    s2 += __shfl_xor(s2, off);
    s3 += __shfl_xor(s3, off);
  }
  if ((tid & 63) == 0) { red[wv][0] = s0; red[wv][1] = s1; red[wv][2] = s2; red[wv][3] = s3; }
  __syncthreads();
  if (tid < 4)
    sinv[tid] = 1.f / (red[0][tid] + red[1][tid] + red[2][tid] + red[3][tid] + 1e-16f);
  __syncthreads();
  float i0 = sinv[0], i1 = sinv[1], i2 = sinv[2], i3 = sinv[3];
  float mh[4] = {m0, m1, m2, m3};
  float ih[4] = {i0, i1, i2, i3};

  // phase C: weighted gather-accumulate
  int c = tid, hh = tid >> 6;
  float accv = 0.f;
  for (int base = e0; base < e1; base += CHUNK) {
    int cntc = min(CHUNK, e1 - base);
    __syncthreads();
    for (int idx = tid; idx < cntc; idx += 256) sbuf[idx] = srcs[base + idx];
    for (int idx = tid; idx < cntc * 4; idx += 256) {
      int j = idx >> 2, hdr = idx & 3;
      int s = srcs[base + j];
      float l = leaky02(as_[s * 4 + hdr] + ((const float*)&adv)[hdr]);
      wbuf[idx] = expf(l - mh[hdr]) * ih[hdr];
    }
    __syncthreads();
    for (int jj = 0; jj < cntc; ++jj) {
      int s = sbuf[jj];
      accv = fmaf(h[(size_t)s * 256 + c], wbuf[jj * 4 + hh], accv);
    }
  }
  float b = bias ? bias[c] : 0.f;
  out[(size_t)n * 256 + c] = accv + b;
}

// ---------------- BatchNorm ----------------
__global__ __launch_bounds__(256) void bnstats_kernel(const float* __restrict__ x,
                                                      float* __restrict__ sum, float* __restrict__ ss,
                                                      int N, int C) {
  int tid = threadIdx.x;
  int f = tid % C;
  int rpb = 256 / C;
  int r = blockIdx.x * rpb + tid / C;
  int stride = gridDim.x * rpb;
  float a = 0.f, b = 0.f;
  for (; r < N; r += stride) {
    float v = x[(size_t)r * C + f];
    a += v;
    b += v * v;
  }
  atomicAdd(&sum[f], a);
  atomicAdd(&ss[f], b);
}

__global__ void bnfinalize_kernel(const float* __restrict__ sum, const float* __restrict__ ss,
                                  const float* __restrict__ gamma, const float* __restrict__ beta,
                                  float* __restrict__ scale, float* __restrict__ shift, int N, int C) {
  int f = threadIdx.x;
  if (f >= C) return;
  float mu = sum[f] / (float)N;
  float var = ss[f] / (float)N - mu * mu;
  float sc = gamma[f] * rsqrtf(var + 1e-5f);
  scale[f] = sc;
  shift[f] = beta[f] - mu * sc;
}

__global__ void bnapply_prelu_kernel(float* __restrict__ x, const float* __restrict__ scale,
                                     const float* __restrict__ shift, const float* __restrict__ pw,
                                     int total, int C) {
  int i = blockIdx.x * 256 + threadIdx.x;
  if (i >= total) return;
  int f = i % C;
  float v = fmaf(x[i], scale[f], shift[f]);
  x[i] = v >= 0.f ? v : pw[0] * v;
}

__global__ void bnapply_elu_kernel(float* __restrict__ x, const float* __restrict__ scale,
                                   const float* __restrict__ shift, int total, int C) {
  int i = blockIdx.x * 256 + threadIdx.x;
  if (i >= total) return;
  int f = i % C;
  float v = fmaf(x[i], scale[f], shift[f]);
  x[i] = v > 0.f ? v : expm1f(v);
}

// ---------------- mean over heads + bias ----------------
__global__ void meanheads_kernel(const float* __restrict__ out2, const float* __restrict__ b2,
                                 float* __restrict__ xm, int N) {
  int i = blockIdx.x * 256 + threadIdx.x;
  if (i >= N * 64) return;
  int n = i >> 6, c = i & 63;
  const float* r = &out2[(size_t)n * 256];
  xm[i] = 0.25f * (r[c] + r[64 + c] + r[128 + c] + r[192 + c]) + b2[c];
}

// ---------------- final FC: [N,64]@[64,86]+b ----------------
__global__ __launch_bounds__(256) void fc_kernel(const float* __restrict__ x, const float* __restrict__ W,
                                                 const float* __restrict__ b, float* __restrict__ out, int N) {
  __shared__ float ws[64 * 86];
  __shared__ float xs[32 * 64];
  int tid = threadIdx.x;
  for (int i = tid; i < 64 * 86; i += 256) ws[i] = W[i];
  int n0 = blockIdx.x * 32;
  for (int i = tid; i < 32 * 64; i += 256) {
    int n = n0 + (i >> 6);
    xs[i] = (n < N) ? x[(size_t)n * 64 + (i & 63)] : 0.f;
  }
  __syncthreads();
  for (int idx = tid; idx < 32 * 86; idx += 256) {
    int nl = idx / 86, o = idx % 86;
    int n = n0 + nl;
    if (n >= N) continue;
    float acc = b[o];
    const float* xr = &xs[nl * 64];
#pragma unroll 8
    for (int k = 0; k < 64; ++k) acc = fmaf(xr[k], ws[k * 86 + o], acc);
    out[(size_t)n * 86 + o] = acc;
  }
}

extern "C" void kernel_launch(void* const* d_in, const int* in_sizes, int n_in,
                              void* d_out, int out_size, void* d_ws, size_t ws_size,
                              hipStream_t stream) {
  const float* x    = (const float*)d_in[0];
  const int*   ei   = (const int*)d_in[1];
  const float* W1   = (const float*)d_in[2];
  const float* asw1 = (const float*)d_in[3];
  const float* adw1 = (const float*)d_in[4];
  const float* b1   = (const float*)d_in[5];
  const float* W2   = (const float*)d_in[6];
  const float* asw2 = (const float*)d_in[7];
  const float* adw2 = (const float*)d_in[8];
  const float* b2   = (const float*)d_in[9];
  const float* g1   = (const float*)d_in[10];
  const float* be1  = (const float*)d_in[11];
  const float* g2   = (const float*)d_in[12];
  const float* be2  = (const float*)d_in[13];
  const float* pw   = (const float*)d_in[14];
  const float* fcW  = (const float*)d_in[15];
  const float* fcb  = (const float*)d_in[16];

  const int N = in_sizes[0] / 256;
  const int E = in_sizes[1] / 2;
  const int EP = E + N;

  char* ws = (char*)d_ws;
  size_t off = 0;
  auto alloc = [&](size_t bytes) {
    char* p = ws + off;
    off += (bytes + 255) & ~(size_t)255;
    return p;
  };
  float* h1   = (float*)alloc((size_t)N * 256 * 4);
  float* outb = (float*)alloc((size_t)N * 256 * 4);
  float* xm   = (float*)alloc((size_t)N * 64 * 4);
  float* as1  = (float*)alloc((size_t)N * 4 * 4);
  float* ad1  = (float*)alloc((size_t)N * 4 * 4);
  float* as2  = (float*)alloc((size_t)N * 4 * 4);
  float* ad2  = (float*)alloc((size_t)N * 4 * 4);
  int* rowptr = (int*)alloc((size_t)(N + 1) * 4);
  int* cnt    = (int*)alloc((size_t)N * 4);
  int* cursor = (int*)alloc((size_t)N * 4);
  int* srcs   = (int*)alloc((size_t)EP * 4);
  float* bsum = (float*)alloc(256 * 4);
  float* bss  = (float*)alloc(256 * 4);
  float* bsc  = (float*)alloc(256 * 4);
  float* bsh  = (float*)alloc(256 * 4);

  int egrid = (EP + 255) / 256;
  dim3 ggrid((N + BM - 1) / BM, 256 / BNT);

  // CSR build
  hipMemsetAsync(cnt, 0, (size_t)N * 4, stream);
  count_kernel<<<egrid, 256, 0, stream>>>(ei, cnt, E, N);
  scan_kernel<<<1, 1024, 0, stream>>>(cnt, rowptr, cursor, N);
  fill_kernel<<<egrid, 256, 0, stream>>>(ei, cursor, srcs, E, N);

  // ---- layer 1 ----
  gemm_kernel<<<ggrid, 256, 0, stream>>>(x, W1, h1, N, 256, 256);
  attdot_kernel<<<N, 256, 0, stream>>>(h1, asw1, adw1, as1, ad1);
  agg_kernel<<<N, 256, 0, stream>>>(h1, as1, ad1, rowptr, srcs, b1, outb);

  hipMemsetAsync(bsum, 0, 256 * 4, stream);
  hipMemsetAsync(bss, 0, 256 * 4, stream);
  bnstats_kernel<<<512, 256, 0, stream>>>(outb, bsum, bss, N, 256);
  bnfinalize_kernel<<<1, 256, 0, stream>>>(bsum, bss, g1, be1, bsc, bsh, N, 256);
  bnapply_prelu_kernel<<<(N * 256 + 255) / 256, 256, 0, stream>>>(outb, bsc, bsh, pw, N * 256, 256);

  // ---- layer 2 ----
  gemm_kernel<<<ggrid, 256, 0, stream>>>(outb, W2, h1, N, 256, 256);
  attdot_kernel<<<N, 256, 0, stream>>>(h1, asw2, adw2, as2, ad2);
  agg_kernel<<<N, 256, 0, stream>>>(h1, as2, ad2, rowptr, srcs, nullptr, outb);
  meanheads_kernel<<<(N * 64 + 255) / 256, 256, 0, stream>>>(outb, b2, xm, N);

  hipMemsetAsync(bsum, 0, 64 * 4, stream);
  hipMemsetAsync(bss, 0, 64 * 4, stream);
  bnstats_kernel<<<512, 256, 0, stream>>>(xm, bsum, bss, N, 64);
  bnfinalize_kernel<<<1, 64, 0, stream>>>(bsum, bss, g2, be2, bsc, bsh, N, 64);
  bnapply_elu_kernel<<<(N * 64 + 255) / 256, 256, 0, stream>>>(xm, bsc, bsh, N * 64, 64);

  // ---- final FC ----
  fc_kernel<<<(N + 31) / 32, 256, 0, stream>>>(xm, fcW, fcb, (float*)d_out, N);
}

// Round 3
// 752.850 us; speedup vs baseline: 1.4089x; 1.4089x over previous
//
#include <hip/hip_runtime.h>
#include <math.h>

#define LEAKY 0.2f

typedef __attribute__((ext_vector_type(8))) short short8;   // 8 bf16 (4 VGPRs)
typedef __attribute__((ext_vector_type(4))) float f32x4;    // 4 fp32

__device__ __forceinline__ float leaky02(float z) { return z >= 0.f ? z : LEAKY * z; }
__device__ __forceinline__ unsigned short f2bf(float f) {
  unsigned u = __float_as_uint(f);
  unsigned r = u + 0x7fffu + ((u >> 16) & 1u);   // RNE
  return (unsigned short)(r >> 16);
}
__device__ __forceinline__ float bf2f(unsigned short s) {
  return __uint_as_float(((unsigned)s) << 16);
}

// ---------------- CSR build ----------------
__global__ void count_kernel(const int* __restrict__ ei, int* __restrict__ cnt, int E, int N) {
  int e = blockIdx.x * 256 + threadIdx.x;
  int EP = E + N;
  if (e >= EP) return;
  int d = (e < E) ? ei[E + e] : (e - E);
  atomicAdd(&cnt[d], 1);
}

__global__ __launch_bounds__(1024) void scan_kernel(const int* __restrict__ cnt,
                                                    int* __restrict__ rowptr,
                                                    int* __restrict__ cursor, int n) {
  __shared__ int wsum[16];
  int tid = threadIdx.x;
  int lane = tid & 63, wv = tid >> 6;
  if (tid == 0) rowptr[0] = 0;
  int carry = 0;
  for (int base = 0; base < n; base += 1024) {
    int i = base + tid;
    int v = (i < n) ? cnt[i] : 0;
    int x = v;
#pragma unroll
    for (int off = 1; off < 64; off <<= 1) {
      int t = __shfl_up(x, off);
      if (lane >= off) x += t;
    }
    if (lane == 63) wsum[wv] = x;
    __syncthreads();
    if (wv == 0 && lane < 16) {
      int y = wsum[lane];
#pragma unroll
      for (int off = 1; off < 16; off <<= 1) {
        int t = __shfl_up(y, off);
        if (lane >= off) y += t;
      }
      wsum[lane] = y;
    }
    __syncthreads();
    int woff = (wv == 0) ? 0 : wsum[wv - 1];
    int incl = x + woff;
    if (i < n) {
      rowptr[i + 1] = carry + incl;
      cursor[i] = carry + incl - v;
    }
    int total = wsum[15];
    __syncthreads();
    carry += total;
  }
}

__global__ void fill_kernel(const int* __restrict__ ei, int* __restrict__ cursor,
                            int* __restrict__ srcs, int E, int N) {
  int e = blockIdx.x * 256 + threadIdx.x;
  int EP = E + N;
  if (e >= EP) return;
  int s, d;
  if (e < E) { s = ei[e]; d = ei[E + e]; } else { s = e - E; d = s; }
  int slot = atomicAdd(&cursor[d], 1);
  srcs[slot] = s;
}

// ---------------- weight convert: Wt[c][k] = bf16(W[k][c]) ----------------
__global__ void convw_kernel(const float* __restrict__ W1, const float* __restrict__ W2,
                             unsigned short* __restrict__ Wt1, unsigned short* __restrict__ Wt2) {
  int idx = blockIdx.x * 256 + threadIdx.x;   // 0..131071
  const float* W;
  unsigned short* Wt;
  if (idx < 65536) { W = W1; Wt = Wt1; } else { W = W2; Wt = Wt2; idx -= 65536; }
  int c = idx >> 8, k = idx & 255;
  Wt[c * 256 + k] = f2bf(W[k * 256 + c]);
}

// ---------------- bf16 MFMA GEMM: H[M,256] = bf16( f(A[M,256]) @ W ) ----------------
// Wt is W transposed [256][256] bf16. Optional fused BN scale/shift + PReLU on A.
__global__ __launch_bounds__(256) void gemm_bf16_kernel(const float* __restrict__ A,
                                                        const unsigned short* __restrict__ Wt,
                                                        unsigned short* __restrict__ Hout, int M,
                                                        const float* __restrict__ bnsc,
                                                        const float* __restrict__ bnsh,
                                                        const float* __restrict__ pw) {
  __shared__ unsigned short As[128][40];   // +8 pad: 80B row stride -> conflict-free b128 reads
  __shared__ unsigned short Bs[128][40];
  int tid = threadIdx.x;
  int bm = blockIdx.x * 128;
  int bn = blockIdx.y * 128;
  int l = tid & 63;
  int wv = tid >> 6;
  int wm = wv >> 1, wn = wv & 1;           // 2x2 waves, 64x64 per wave
  int lr = l & 15, lk = l >> 4;            // fragment row/col = l&15, k-group = l>>4

  f32x4 acc[4][4] = {};
  float pws = pw ? pw[0] : 0.f;

  for (int k0 = 0; k0 < 256; k0 += 32) {
    // stage A tile (fp32 -> optional BN+PReLU -> bf16)
#pragma unroll
    for (int i = tid; i < 1024; i += 256) {
      int row = i >> 3, kk = (i & 7) * 4;
      int gr = bm + row;
      float4 va = make_float4(0.f, 0.f, 0.f, 0.f);
      if (gr < M) va = *(const float4*)&A[(size_t)gr * 256 + k0 + kk];
      if (bnsc) {
        float4 sc = *(const float4*)&bnsc[k0 + kk];
        float4 sh = *(const float4*)&bnsh[k0 + kk];
        va.x = fmaf(va.x, sc.x, sh.x); va.y = fmaf(va.y, sc.y, sh.y);
        va.z = fmaf(va.z, sc.z, sh.z); va.w = fmaf(va.w, sc.w, sh.w);
        va.x = va.x >= 0.f ? va.x : va.x * pws;
        va.y = va.y >= 0.f ? va.y : va.y * pws;
        va.z = va.z >= 0.f ? va.z : va.z * pws;
        va.w = va.w >= 0.f ? va.w : va.w * pws;
      }
      ushort4 u;
      u.x = f2bf(va.x); u.y = f2bf(va.y); u.z = f2bf(va.z); u.w = f2bf(va.w);
      *(ushort4*)&As[row][kk] = u;
    }
    // stage B tile (bf16 W^T rows, already k-contiguous)
#pragma unroll
    for (int i = tid; i < 1024; i += 256) {
      int c = i >> 3, kk = (i & 7) * 4;
      ushort4 u = *(const ushort4*)&Wt[(size_t)(bn + c) * 256 + k0 + kk];
      *(ushort4*)&Bs[c][kk] = u;
    }
    __syncthreads();
    short8 af[4], bfr[4];
#pragma unroll
    for (int mt = 0; mt < 4; ++mt)
      af[mt] = *(const short8*)&As[wm * 64 + mt * 16 + lr][lk * 8];
#pragma unroll
    for (int nt = 0; nt < 4; ++nt)
      bfr[nt] = *(const short8*)&Bs[wn * 64 + nt * 16 + lr][lk * 8];
#pragma unroll
    for (int mt = 0; mt < 4; ++mt)
#pragma unroll
      for (int nt = 0; nt < 4; ++nt)
        acc[mt][nt] = __builtin_amdgcn_mfma_f32_16x16x32_bf16(af[mt], bfr[nt], acc[mt][nt], 0, 0, 0);
    __syncthreads();
  }
  // epilogue: D mapping col=lane&15, row=(lane>>4)*4+reg  [m89]
#pragma unroll
  for (int mt = 0; mt < 4; ++mt) {
#pragma unroll
    for (int r = 0; r < 4; ++r) {
      int gr = bm + wm * 64 + mt * 16 + lk * 4 + r;
      if (gr >= M) continue;
#pragma unroll
      for (int nt = 0; nt < 4; ++nt) {
        int gc = bn + wn * 64 + nt * 16 + lr;
        Hout[(size_t)gr * 256 + gc] = f2bf(acc[mt][nt][r]);
      }
    }
  }
}

// ---------------- attention dots: wave per node, bf16 h ----------------
__global__ __launch_bounds__(256) void attdot_kernel(const unsigned short* __restrict__ h,
                                                     const float* __restrict__ att_s,
                                                     const float* __restrict__ att_d,
                                                     float* __restrict__ as_, float* __restrict__ ad_,
                                                     int N) {
  int l = threadIdx.x & 63;
  int n = blockIdx.x * 4 + (threadIdx.x >> 6);
  if (n >= N) return;
  uint2 hv = *(const uint2*)&h[(size_t)n * 256 + l * 4];
  float4 s4 = *(const float4*)&att_s[l * 4];
  float4 d4 = *(const float4*)&att_d[l * 4];
  float h0 = bf2f((unsigned short)(hv.x & 0xffff));
  float h1 = bf2f((unsigned short)(hv.x >> 16));
  float h2 = bf2f((unsigned short)(hv.y & 0xffff));
  float h3 = bf2f((unsigned short)(hv.y >> 16));
  float ps = h0 * s4.x + h1 * s4.y + h2 * s4.z + h3 * s4.w;
  float pd = h0 * d4.x + h1 * d4.y + h2 * d4.z + h3 * d4.w;
#pragma unroll
  for (int off = 1; off < 16; off <<= 1) {
    ps += __shfl_xor(ps, off);
    pd += __shfl_xor(pd, off);
  }
  if ((l & 15) == 0) {
    as_[n * 4 + (l >> 4)] = ps;
    ad_[n * 4 + (l >> 4)] = pd;
  }
}

// ---------------- GAT aggregation: wave per node, no LDS, bf16 gather ----------------
__global__ __launch_bounds__(256) void agg_kernel(const unsigned short* __restrict__ h,
                                                  const float* __restrict__ as_,
                                                  const float* __restrict__ ad_,
                                                  const int* __restrict__ rowptr,
                                                  const int* __restrict__ srcs,
                                                  const float* __restrict__ bias,
                                                  float* __restrict__ out, int N, int concat) {
  int l = threadIdx.x & 63;
  int n = blockIdx.x * 4 + (threadIdx.x >> 6);
  if (n >= N) return;
  int e0 = rowptr[n], e1 = rowptr[n + 1];
  float4 adv = *(const float4*)&ad_[n * 4];
  float ad[4] = {adv.x, adv.y, adv.z, adv.w};

  // per-head max
  float mx[4] = {-1e30f, -1e30f, -1e30f, -1e30f};
  for (int j = e0 + l; j < e1; j += 64) {
    int s = srcs[j];
    float4 av = *(const float4*)&as_[s * 4];
    mx[0] = fmaxf(mx[0], leaky02(av.x + ad[0]));
    mx[1] = fmaxf(mx[1], leaky02(av.y + ad[1]));
    mx[2] = fmaxf(mx[2], leaky02(av.z + ad[2]));
    mx[3] = fmaxf(mx[3], leaky02(av.w + ad[3]));
  }
#pragma unroll
  for (int off = 32; off; off >>= 1) {
    mx[0] = fmaxf(mx[0], __shfl_xor(mx[0], off));
    mx[1] = fmaxf(mx[1], __shfl_xor(mx[1], off));
    mx[2] = fmaxf(mx[2], __shfl_xor(mx[2], off));
    mx[3] = fmaxf(mx[3], __shfl_xor(mx[3], off));
  }
  // per-head sum of exp
  float sm[4] = {0.f, 0.f, 0.f, 0.f};
  for (int j = e0 + l; j < e1; j += 64) {
    int s = srcs[j];
    float4 av = *(const float4*)&as_[s * 4];
    sm[0] += expf(leaky02(av.x + ad[0]) - mx[0]);
    sm[1] += expf(leaky02(av.y + ad[1]) - mx[1]);
    sm[2] += expf(leaky02(av.z + ad[2]) - mx[2]);
    sm[3] += expf(leaky02(av.w + ad[3]) - mx[3]);
  }
#pragma unroll
  for (int off = 32; off; off >>= 1) {
    sm[0] += __shfl_xor(sm[0], off);
    sm[1] += __shfl_xor(sm[1], off);
    sm[2] += __shfl_xor(sm[2], off);
    sm[3] += __shfl_xor(sm[3], off);
  }
  int hh = l >> 4;
  float mh = mx[hh];
  float ih = 1.f / (sm[hh] + 1e-16f);
  float adh = ad[hh];

  float a0 = 0.f, a1 = 0.f, a2 = 0.f, a3 = 0.f;
  for (int j = e0; j < e1; ++j) {
    int s = srcs[j];
    float al = expf(leaky02(as_[s * 4 + hh] + adh) - mh) * ih;
    uint2 hv = *(const uint2*)&h[(size_t)s * 256 + l * 4];
    a0 = fmaf(bf2f((unsigned short)(hv.x & 0xffff)), al, a0);
    a1 = fmaf(bf2f((unsigned short)(hv.x >> 16)), al, a1);
    a2 = fmaf(bf2f((unsigned short)(hv.y & 0xffff)), al, a2);
    a3 = fmaf(bf2f((unsigned short)(hv.y >> 16)), al, a3);
  }
  if (concat) {
    float4 b4 = *(const float4*)&bias[l * 4];
    float4 o = make_float4(a0 + b4.x, a1 + b4.y, a2 + b4.z, a3 + b4.w);
    *(float4*)&out[(size_t)n * 256 + l * 4] = o;
  } else {
    // mean over heads: channels differ by 64 across lane groups of 16
    a0 += __shfl_xor(a0, 16); a0 += __shfl_xor(a0, 32);
    a1 += __shfl_xor(a1, 16); a1 += __shfl_xor(a1, 32);
    a2 += __shfl_xor(a2, 16); a2 += __shfl_xor(a2, 32);
    a3 += __shfl_xor(a3, 16); a3 += __shfl_xor(a3, 32);
    if (l < 16) {
      float4 b4 = *(const float4*)&bias[l * 4];
      float4 o = make_float4(0.25f * a0 + b4.x, 0.25f * a1 + b4.y,
                             0.25f * a2 + b4.z, 0.25f * a3 + b4.w);
      *(float4*)&out[(size_t)n * 64 + l * 4] = o;
    }
  }
}

// ---------------- BatchNorm ----------------
__global__ __launch_bounds__(256) void bnstats_kernel(const float* __restrict__ x,
                                                      float* __restrict__ sum, float* __restrict__ ss,
                                                      int N, int C) {
  int tid = threadIdx.x;
  int f = tid % C;
  int rpb = 256 / C;
  int r = blockIdx.x * rpb + tid / C;
  int stride = gridDim.x * rpb;
  float a = 0.f, b = 0.f;
  for (; r < N; r += stride) {
    float v = x[(size_t)r * C + f];
    a += v;
    b += v * v;
  }
  atomicAdd(&sum[f], a);
  atomicAdd(&ss[f], b);
}

__global__ void bnfinalize_kernel(const float* __restrict__ sum, const float* __restrict__ ss,
                                  const float* __restrict__ gamma, const float* __restrict__ beta,
                                  float* __restrict__ scale, float* __restrict__ shift, int N, int C) {
  int f = threadIdx.x;
  if (f >= C) return;
  float mu = sum[f] / (float)N;
  float var = ss[f] / (float)N - mu * mu;
  float sc = gamma[f] * rsqrtf(var + 1e-5f);
  scale[f] = sc;
  shift[f] = beta[f] - mu * sc;
}

// ---------------- final FC with fused BN2 + ELU: [N,64]@[64,86]+b ----------------
__global__ __launch_bounds__(256) void fc_kernel(const float* __restrict__ x,
                                                 const float* __restrict__ sc, const float* __restrict__ sh,
                                                 const float* __restrict__ W, const float* __restrict__ b,
                                                 float* __restrict__ out, int N) {
  __shared__ float ws[64 * 86];
  __shared__ float xs[32 * 64];
  int tid = threadIdx.x;
  for (int i = tid; i < 64 * 86; i += 256) ws[i] = W[i];
  int n0 = blockIdx.x * 32;
  for (int i = tid; i < 32 * 64; i += 256) {
    int n = n0 + (i >> 6), c = i & 63;
    float v = (n < N) ? x[(size_t)n * 64 + c] : 0.f;
    v = fmaf(v, sc[c], sh[c]);
    xs[i] = v > 0.f ? v : expm1f(v);
  }
  __syncthreads();
  for (int idx = tid; idx < 32 * 86; idx += 256) {
    int nl = idx / 86, o = idx % 86;
    int n = n0 + nl;
    if (n >= N) continue;
    float acc = b[o];
    const float* xr = &xs[nl * 64];
#pragma unroll 8
    for (int k = 0; k < 64; ++k) acc = fmaf(xr[k], ws[k * 86 + o], acc);
    out[(size_t)n * 86 + o] = acc;
  }
}

extern "C" void kernel_launch(void* const* d_in, const int* in_sizes, int n_in,
                              void* d_out, int out_size, void* d_ws, size_t ws_size,
                              hipStream_t stream) {
  const float* x    = (const float*)d_in[0];
  const int*   ei   = (const int*)d_in[1];
  const float* W1   = (const float*)d_in[2];
  const float* asw1 = (const float*)d_in[3];
  const float* adw1 = (const float*)d_in[4];
  const float* b1   = (const float*)d_in[5];
  const float* W2   = (const float*)d_in[6];
  const float* asw2 = (const float*)d_in[7];
  const float* adw2 = (const float*)d_in[8];
  const float* b2   = (const float*)d_in[9];
  const float* g1   = (const float*)d_in[10];
  const float* be1  = (const float*)d_in[11];
  const float* g2   = (const float*)d_in[12];
  const float* be2  = (const float*)d_in[13];
  const float* pw   = (const float*)d_in[14];
  const float* fcW  = (const float*)d_in[15];
  const float* fcb  = (const float*)d_in[16];

  const int N = in_sizes[0] / 256;
  const int E = in_sizes[1] / 2;
  const int EP = E + N;

  char* ws = (char*)d_ws;
  size_t off = 0;
  auto alloc = [&](size_t bytes) {
    char* p = ws + off;
    off += (bytes + 255) & ~(size_t)255;
    return p;
  };
  unsigned short* h   = (unsigned short*)alloc((size_t)N * 256 * 2);  // bf16 hidden
  float* outb = (float*)alloc((size_t)N * 256 * 4);                    // fp32 layer-1 out
  float* xm   = (float*)alloc((size_t)N * 64 * 4);                     // fp32 layer-2 out (mean)
  float* as1  = (float*)alloc((size_t)N * 4 * 4);
  float* ad1  = (float*)alloc((size_t)N * 4 * 4);
  float* as2  = (float*)alloc((size_t)N * 4 * 4);
  float* ad2  = (float*)alloc((size_t)N * 4 * 4);
  int* rowptr = (int*)alloc((size_t)(N + 1) * 4);
  int* cnt    = (int*)alloc((size_t)N * 4);
  int* cursor = (int*)alloc((size_t)N * 4);
  int* srcs   = (int*)alloc((size_t)EP * 4);
  unsigned short* Wt1 = (unsigned short*)alloc(65536 * 2);
  unsigned short* Wt2 = (unsigned short*)alloc(65536 * 2);
  float* bsum = (float*)alloc(256 * 4);
  float* bss  = (float*)alloc(256 * 4);
  float* bsc  = (float*)alloc(256 * 4);
  float* bsh  = (float*)alloc(256 * 4);
  float* bsc2 = (float*)alloc(64 * 4);
  float* bsh2 = (float*)alloc(64 * 4);

  int egrid = (EP + 255) / 256;
  int ngrid4 = (N + 3) / 4;
  dim3 ggrid((N + 127) / 128, 2);

  // CSR build + weight conversion
  hipMemsetAsync(cnt, 0, (size_t)N * 4, stream);
  count_kernel<<<egrid, 256, 0, stream>>>(ei, cnt, E, N);
  convw_kernel<<<512, 256, 0, stream>>>(W1, W2, Wt1, Wt2);
  scan_kernel<<<1, 1024, 0, stream>>>(cnt, rowptr, cursor, N);
  fill_kernel<<<egrid, 256, 0, stream>>>(ei, cursor, srcs, E, N);

  // ---- layer 1 ----
  gemm_bf16_kernel<<<ggrid, 256, 0, stream>>>(x, Wt1, h, N, nullptr, nullptr, nullptr);
  attdot_kernel<<<ngrid4, 256, 0, stream>>>(h, asw1, adw1, as1, ad1, N);
  agg_kernel<<<ngrid4, 256, 0, stream>>>(h, as1, ad1, rowptr, srcs, b1, outb, N, 1);

  hipMemsetAsync(bsum, 0, 256 * 4, stream);
  hipMemsetAsync(bss, 0, 256 * 4, stream);
  bnstats_kernel<<<512, 256, 0, stream>>>(outb, bsum, bss, N, 256);
  bnfinalize_kernel<<<1, 256, 0, stream>>>(bsum, bss, g1, be1, bsc, bsh, N, 256);

  // ---- layer 2 (BN1+PReLU fused into GEMM2 A-staging) ----
  gemm_bf16_kernel<<<ggrid, 256, 0, stream>>>(outb, Wt2, h, N, bsc, bsh, pw);
  attdot_kernel<<<ngrid4, 256, 0, stream>>>(h, asw2, adw2, as2, ad2, N);
  agg_kernel<<<ngrid4, 256, 0, stream>>>(h, as2, ad2, rowptr, srcs, b2, xm, N, 0);

  hipMemsetAsync(bsum, 0, 64 * 4, stream);
  hipMemsetAsync(bss, 0, 64 * 4, stream);
  bnstats_kernel<<<512, 256, 0, stream>>>(xm, bsum, bss, N, 64);
  bnfinalize_kernel<<<1, 64, 0, stream>>>(bsum, bss, g2, be2, bsc2, bsh2, N, 64);

  // ---- final FC (BN2 + ELU fused) ----
  fc_kernel<<<(N + 31) / 32, 256, 0, stream>>>(xm, bsc2, bsh2, fcW, fcb, (float*)d_out, N);
}

// Round 4
// 607.807 us; speedup vs baseline: 1.7452x; 1.2386x over previous
//
#include <hip/hip_runtime.h>
#include <math.h>

#define LEAKY 0.2f

typedef __attribute__((ext_vector_type(8))) short short8;   // 8 bf16 (4 VGPRs)
typedef __attribute__((ext_vector_type(4))) float f32x4;    // 4 fp32

__device__ __forceinline__ float leaky02(float z) { return z >= 0.f ? z : LEAKY * z; }
__device__ __forceinline__ unsigned short f2bf(float f) {
  unsigned u = __float_as_uint(f);
  unsigned r = u + 0x7fffu + ((u >> 16) & 1u);   // RNE
  return (unsigned short)(r >> 16);
}
__device__ __forceinline__ float bflo(unsigned u) { return __uint_as_float(u << 16); }
__device__ __forceinline__ float bfhi(unsigned u) { return __uint_as_float(u & 0xffff0000u); }

// ---------------- CSR build ----------------
__global__ void count_kernel(const int* __restrict__ ei, int* __restrict__ cnt, int E, int N) {
  int e = blockIdx.x * 256 + threadIdx.x;
  int EP = E + N;
  if (e >= EP) return;
  int d = (e < E) ? ei[E + e] : (e - E);
  atomicAdd(&cnt[d], 1);
}

__global__ __launch_bounds__(256) void scan1_kernel(const int* __restrict__ cnt,
                                                    int* __restrict__ bsums, int n) {
  int i = blockIdx.x * 256 + threadIdx.x;
  int v = (i < n) ? cnt[i] : 0;
  int lane = threadIdx.x & 63, wv = threadIdx.x >> 6;
#pragma unroll
  for (int off = 32; off; off >>= 1) v += __shfl_xor(v, off);
  __shared__ int w[4];
  if (lane == 0) w[wv] = v;
  __syncthreads();
  if (threadIdx.x == 0) bsums[blockIdx.x] = w[0] + w[1] + w[2] + w[3];
}

__global__ __launch_bounds__(256) void scan2_kernel(int* __restrict__ bsums, int nb) {
  int tid = threadIdx.x;
  int lane = tid & 63, wv = tid >> 6;
  int v = (tid < nb) ? bsums[tid] : 0;
  int x = v;
#pragma unroll
  for (int off = 1; off < 64; off <<= 1) {
    int t = __shfl_up(x, off);
    if (lane >= off) x += t;
  }
  __shared__ int ws[4];
  if (lane == 63) ws[wv] = x;
  __syncthreads();
  int woff = 0;
#pragma unroll
  for (int w = 0; w < 4; ++w) if (w < wv) woff += ws[w];
  if (tid < nb) bsums[tid] = x + woff - v;   // exclusive
}

__global__ __launch_bounds__(256) void scan3_kernel(const int* __restrict__ cnt,
                                                    const int* __restrict__ boff,
                                                    int* __restrict__ rowptr,
                                                    int* __restrict__ cursor, int n) {
  int i = blockIdx.x * 256 + threadIdx.x;
  int tid = threadIdx.x, lane = tid & 63, wv = tid >> 6;
  int v = (i < n) ? cnt[i] : 0;
  int x = v;
#pragma unroll
  for (int off = 1; off < 64; off <<= 1) {
    int t = __shfl_up(x, off);
    if (lane >= off) x += t;
  }
  __shared__ int ws[4];
  if (lane == 63) ws[wv] = x;
  __syncthreads();
  int woff = 0;
#pragma unroll
  for (int w = 0; w < 4; ++w) if (w < wv) woff += ws[w];
  int incl = x + woff;
  int base = boff[blockIdx.x];
  if (i < n) {
    rowptr[i + 1] = base + incl;
    cursor[i] = base + incl - v;
  }
  if (i == 0) rowptr[0] = 0;
}

__global__ void fill_kernel(const int* __restrict__ ei, int* __restrict__ cursor,
                            int* __restrict__ srcs, int E, int N) {
  int e = blockIdx.x * 256 + threadIdx.x;
  int EP = E + N;
  if (e >= EP) return;
  int s, d;
  if (e < E) { s = ei[e]; d = ei[E + e]; } else { s = e - E; d = s; }
  int slot = atomicAdd(&cursor[d], 1);
  srcs[slot] = s;
}

// ---------------- weight convert: Wt[c][k] = bf16(W[k][c]) ----------------
__global__ void convw_kernel(const float* __restrict__ W1, const float* __restrict__ W2,
                             unsigned short* __restrict__ Wt1, unsigned short* __restrict__ Wt2) {
  int idx = blockIdx.x * 256 + threadIdx.x;   // 0..131071
  const float* W;
  unsigned short* Wt;
  if (idx < 65536) { W = W1; Wt = Wt1; } else { W = W2; Wt = Wt2; idx -= 65536; }
  int c = idx >> 8, k = idx & 255;
  Wt[c * 256 + k] = f2bf(W[k * 256 + c]);
}

// ---------------- bf16 MFMA GEMM, full-width 128x256 tile, 8 waves ----------------
// Fused: optional BN+PReLU on A; attention dots as/ad from fp32 acc in epilogue.
template <bool BF16A>
__global__ __launch_bounds__(512) void gemm_kernel(const void* __restrict__ Av,
                                                   const unsigned short* __restrict__ Wt,
                                                   unsigned short* __restrict__ Hout, int M,
                                                   const float* __restrict__ bnsc,
                                                   const float* __restrict__ bnsh,
                                                   const float* __restrict__ pwp,
                                                   const float* __restrict__ att_s,
                                                   const float* __restrict__ att_d,
                                                   float* __restrict__ as_o,
                                                   float* __restrict__ ad_o) {
  __shared__ unsigned short As[128][40];   // +8 pad
  __shared__ unsigned short Bs[256][40];
  int tid = threadIdx.x;
  int bm = blockIdx.x * 128;
  int l = tid & 63, wv = tid >> 6;
  int wm = wv >> 2, wn = wv & 3;           // 2 x 4 waves; wave tile 64 rows x 64 cols (one head)
  int lr = l & 15, lk = l >> 4;
  f32x4 acc[4][4] = {};
  float pws = pwp ? pwp[0] : 0.f;

  for (int k0 = 0; k0 < 256; k0 += 32) {
    // A: 128 rows x 32 k
#pragma unroll
    for (int it = 0; it < 2; ++it) {
      int i = tid + it * 512;
      int row = i >> 3, kk = (i & 7) * 4;
      int gr = bm + row;
      float v0, v1, v2, v3;
      if (BF16A) {
        uint2 u = make_uint2(0, 0);
        if (gr < M) u = *(const uint2*)((const unsigned short*)Av + (size_t)gr * 256 + k0 + kk);
        v0 = bflo(u.x); v1 = bfhi(u.x); v2 = bflo(u.y); v3 = bfhi(u.y);
      } else {
        float4 va = make_float4(0.f, 0.f, 0.f, 0.f);
        if (gr < M) va = *(const float4*)((const float*)Av + (size_t)gr * 256 + k0 + kk);
        v0 = va.x; v1 = va.y; v2 = va.z; v3 = va.w;
      }
      if (bnsc) {
        float4 sc = *(const float4*)&bnsc[k0 + kk];
        float4 sh = *(const float4*)&bnsh[k0 + kk];
        v0 = fmaf(v0, sc.x, sh.x); v1 = fmaf(v1, sc.y, sh.y);
        v2 = fmaf(v2, sc.z, sh.z); v3 = fmaf(v3, sc.w, sh.w);
        v0 = v0 >= 0.f ? v0 : v0 * pws; v1 = v1 >= 0.f ? v1 : v1 * pws;
        v2 = v2 >= 0.f ? v2 : v2 * pws; v3 = v3 >= 0.f ? v3 : v3 * pws;
      }
      ushort4 u4;
      u4.x = f2bf(v0); u4.y = f2bf(v1); u4.z = f2bf(v2); u4.w = f2bf(v3);
      *(ushort4*)&As[row][kk] = u4;
    }
    // B: 256 cols x 32 k
#pragma unroll
    for (int it = 0; it < 4; ++it) {
      int i = tid + it * 512;
      int c = i >> 3, kk = (i & 7) * 4;
      *(ushort4*)&Bs[c][kk] = *(const ushort4*)&Wt[(size_t)c * 256 + k0 + kk];
    }
    __syncthreads();
    short8 af[4], bfr[4];
#pragma unroll
    for (int mt = 0; mt < 4; ++mt) af[mt] = *(const short8*)&As[wm * 64 + mt * 16 + lr][lk * 8];
#pragma unroll
    for (int nt = 0; nt < 4; ++nt) bfr[nt] = *(const short8*)&Bs[wn * 64 + nt * 16 + lr][lk * 8];
#pragma unroll
    for (int mt = 0; mt < 4; ++mt)
#pragma unroll
      for (int nt = 0; nt < 4; ++nt)
        acc[mt][nt] = __builtin_amdgcn_mfma_f32_16x16x32_bf16(af[mt], bfr[nt], acc[mt][nt], 0, 0, 0);
    __syncthreads();
  }
  // epilogue: C/D map col=lane&15, row=(lane>>4)*4+reg; wave wn owns head wn (64 cols)
  float asv[4], adv[4];
#pragma unroll
  for (int nt = 0; nt < 4; ++nt) {
    int gc = wn * 64 + nt * 16 + lr;
    asv[nt] = att_s[gc];
    adv[nt] = att_d[gc];
  }
#pragma unroll
  for (int mt = 0; mt < 4; ++mt) {
#pragma unroll
    for (int r = 0; r < 4; ++r) {
      int gr = bm + wm * 64 + mt * 16 + lk * 4 + r;
      float ps = acc[mt][0][r] * asv[0] + acc[mt][1][r] * asv[1] +
                 acc[mt][2][r] * asv[2] + acc[mt][3][r] * asv[3];
      float pd = acc[mt][0][r] * adv[0] + acc[mt][1][r] * adv[1] +
                 acc[mt][2][r] * adv[2] + acc[mt][3][r] * adv[3];
#pragma unroll
      for (int off = 1; off < 16; off <<= 1) {
        ps += __shfl_xor(ps, off);
        pd += __shfl_xor(pd, off);
      }
      if (lr == 0 && gr < M) {
        as_o[gr * 4 + wn] = ps;
        ad_o[gr * 4 + wn] = pd;
      }
      if (gr < M) {
#pragma unroll
        for (int nt = 0; nt < 4; ++nt)
          Hout[(size_t)gr * 256 + wn * 64 + nt * 16 + lr] = f2bf(acc[mt][nt][r]);
      }
    }
  }
}

// ---------------- GAT aggregation: wave per node, shuffle-alpha fast path ----------------
__global__ __launch_bounds__(256) void agg_kernel(const unsigned short* __restrict__ h,
                                                  const float* __restrict__ as_,
                                                  const float* __restrict__ ad_,
                                                  const int* __restrict__ rowptr,
                                                  const int* __restrict__ srcs,
                                                  const float* __restrict__ bias,
                                                  unsigned short* __restrict__ out_bf,
                                                  float* __restrict__ out_f,
                                                  int N, int concat) {
  int l = threadIdx.x & 63;
  int n = blockIdx.x * 4 + (threadIdx.x >> 6);
  if (n >= N) return;
  int e0 = rowptr[n], e1 = rowptr[n + 1];
  int deg = e1 - e0;
  int hh = l >> 4, le = l & 15;
  float adh = ad_[n * 4 + hh];
  float a0 = 0.f, a1 = 0.f, a2 = 0.f, a3 = 0.f;

  if (deg <= 64) {
    // lane (le, hh) owns edges e0+le+16t, head hh
    int sidx[4];
    float lg[4];
#pragma unroll
    for (int t = 0; t < 4; ++t) {
      int j = e0 + le + 16 * t;
      if (j < e1) {
        int s = srcs[j];
        sidx[t] = s;
        lg[t] = leaky02(as_[s * 4 + hh] + adh);
      } else {
        sidx[t] = 0;
        lg[t] = -1e30f;
      }
    }
    float mx = fmaxf(fmaxf(lg[0], lg[1]), fmaxf(lg[2], lg[3]));
#pragma unroll
    for (int off = 1; off < 16; off <<= 1) mx = fmaxf(mx, __shfl_xor(mx, off));
    float ex[4];
    float sm = 0.f;
#pragma unroll
    for (int t = 0; t < 4; ++t) {
      ex[t] = (lg[t] > -1e29f) ? __expf(lg[t] - mx) : 0.f;
      sm += ex[t];
    }
#pragma unroll
    for (int off = 1; off < 16; off <<= 1) sm += __shfl_xor(sm, off);
    float inv = 1.f / (sm + 1e-16f);
    int hsel = hh << 4;
#pragma unroll
    for (int t = 0; t < 4; ++t) {
      int base = e0 + 16 * t;
      if (base >= e1) continue;
      int cntc = min(16, e1 - base);
#pragma unroll 4
      for (int q = 0; q < cntc; ++q) {
        int s = __shfl(sidx[t], q);
        float al = __shfl(ex[t], q + hsel) * inv;
        uint2 hv = *(const uint2*)&h[(size_t)s * 256 + l * 4];
        a0 = fmaf(bflo(hv.x), al, a0);
        a1 = fmaf(bfhi(hv.x), al, a1);
        a2 = fmaf(bflo(hv.y), al, a2);
        a3 = fmaf(bfhi(hv.y), al, a3);
      }
    }
  } else {
    // general fallback (deg > 64): strided phases + per-edge exp
    float ad4[4] = {ad_[n * 4], ad_[n * 4 + 1], ad_[n * 4 + 2], ad_[n * 4 + 3]};
    float mx[4] = {-1e30f, -1e30f, -1e30f, -1e30f};
    for (int j = e0 + l; j < e1; j += 64) {
      int s = srcs[j];
      float4 av = *(const float4*)&as_[s * 4];
      mx[0] = fmaxf(mx[0], leaky02(av.x + ad4[0]));
      mx[1] = fmaxf(mx[1], leaky02(av.y + ad4[1]));
      mx[2] = fmaxf(mx[2], leaky02(av.z + ad4[2]));
      mx[3] = fmaxf(mx[3], leaky02(av.w + ad4[3]));
    }
#pragma unroll
    for (int off = 32; off; off >>= 1) {
      mx[0] = fmaxf(mx[0], __shfl_xor(mx[0], off));
      mx[1] = fmaxf(mx[1], __shfl_xor(mx[1], off));
      mx[2] = fmaxf(mx[2], __shfl_xor(mx[2], off));
      mx[3] = fmaxf(mx[3], __shfl_xor(mx[3], off));
    }
    float sm[4] = {0.f, 0.f, 0.f, 0.f};
    for (int j = e0 + l; j < e1; j += 64) {
      int s = srcs[j];
      float4 av = *(const float4*)&as_[s * 4];
      sm[0] += __expf(leaky02(av.x + ad4[0]) - mx[0]);
      sm[1] += __expf(leaky02(av.y + ad4[1]) - mx[1]);
      sm[2] += __expf(leaky02(av.z + ad4[2]) - mx[2]);
      sm[3] += __expf(leaky02(av.w + ad4[3]) - mx[3]);
    }
#pragma unroll
    for (int off = 32; off; off >>= 1) {
      sm[0] += __shfl_xor(sm[0], off);
      sm[1] += __shfl_xor(sm[1], off);
      sm[2] += __shfl_xor(sm[2], off);
      sm[3] += __shfl_xor(sm[3], off);
    }
    float mh = hh == 0 ? mx[0] : hh == 1 ? mx[1] : hh == 2 ? mx[2] : mx[3];
    float sh = hh == 0 ? sm[0] : hh == 1 ? sm[1] : hh == 2 ? sm[2] : sm[3];
    float inv = 1.f / (sh + 1e-16f);
    int j = e0;
    for (; j + 2 <= e1; j += 2) {
      int s0 = srcs[j], s1 = srcs[j + 1];
      float x0 = as_[s0 * 4 + hh], x1 = as_[s1 * 4 + hh];
      uint2 h0 = *(const uint2*)&h[(size_t)s0 * 256 + l * 4];
      uint2 h1 = *(const uint2*)&h[(size_t)s1 * 256 + l * 4];
      float al0 = __expf(leaky02(x0 + adh) - mh) * inv;
      float al1 = __expf(leaky02(x1 + adh) - mh) * inv;
      a0 = fmaf(bflo(h0.x), al0, a0); a1 = fmaf(bfhi(h0.x), al0, a1);
      a2 = fmaf(bflo(h0.y), al0, a2); a3 = fmaf(bfhi(h0.y), al0, a3);
      a0 = fmaf(bflo(h1.x), al1, a0); a1 = fmaf(bfhi(h1.x), al1, a1);
      a2 = fmaf(bflo(h1.y), al1, a2); a3 = fmaf(bfhi(h1.y), al1, a3);
    }
    for (; j < e1; ++j) {
      int s = srcs[j];
      float al = __expf(leaky02(as_[s * 4 + hh] + adh) - mh) * inv;
      uint2 hv = *(const uint2*)&h[(size_t)s * 256 + l * 4];
      a0 = fmaf(bflo(hv.x), al, a0); a1 = fmaf(bfhi(hv.x), al, a1);
      a2 = fmaf(bflo(hv.y), al, a2); a3 = fmaf(bfhi(hv.y), al, a3);
    }
  }

  if (concat) {
    float4 b4 = *(const float4*)&bias[l * 4];
    ushort4 o;
    o.x = f2bf(a0 + b4.x); o.y = f2bf(a1 + b4.y);
    o.z = f2bf(a2 + b4.z); o.w = f2bf(a3 + b4.w);
    *(ushort4*)&out_bf[(size_t)n * 256 + l * 4] = o;
  } else {
    a0 += __shfl_xor(a0, 16); a0 += __shfl_xor(a0, 32);
    a1 += __shfl_xor(a1, 16); a1 += __shfl_xor(a1, 32);
    a2 += __shfl_xor(a2, 16); a2 += __shfl_xor(a2, 32);
    a3 += __shfl_xor(a3, 16); a3 += __shfl_xor(a3, 32);
    if (l < 16) {
      float4 b4 = *(const float4*)&bias[l * 4];
      float4 o = make_float4(0.25f * a0 + b4.x, 0.25f * a1 + b4.y,
                             0.25f * a2 + b4.z, 0.25f * a3 + b4.w);
      *(float4*)&out_f[(size_t)n * 64 + l * 4] = o;
    }
  }
}

// ---------------- BatchNorm stats ----------------
__global__ __launch_bounds__(256) void bnstats_bf16_kernel(const unsigned short* __restrict__ x,
                                                           float* __restrict__ sum,
                                                           float* __restrict__ ss, int N) {
  int tid = threadIdx.x;
  int c = (tid & 127) * 2;
  int r = blockIdx.x * 2 + (tid >> 7);
  int stride = gridDim.x * 2;
  float a0 = 0.f, b0 = 0.f, a1 = 0.f, b1 = 0.f;
  for (; r < N; r += stride) {
    unsigned u = *(const unsigned*)&x[(size_t)r * 256 + c];
    float v0 = bflo(u), v1 = bfhi(u);
    a0 += v0; b0 += v0 * v0;
    a1 += v1; b1 += v1 * v1;
  }
  atomicAdd(&sum[c], a0); atomicAdd(&ss[c], b0);
  atomicAdd(&sum[c + 1], a1); atomicAdd(&ss[c + 1], b1);
}

__global__ __launch_bounds__(256) void bnstats_kernel(const float* __restrict__ x,
                                                      float* __restrict__ sum, float* __restrict__ ss,
                                                      int N, int C) {
  int tid = threadIdx.x;
  int f = tid % C;
  int rpb = 256 / C;
  int r = blockIdx.x * rpb + tid / C;
  int stride = gridDim.x * rpb;
  float a = 0.f, b = 0.f;
  for (; r < N; r += stride) {
    float v = x[(size_t)r * C + f];
    a += v;
    b += v * v;
  }
  atomicAdd(&sum[f], a);
  atomicAdd(&ss[f], b);
}

__global__ void bnfinalize_kernel(const float* __restrict__ sum, const float* __restrict__ ss,
                                  const float* __restrict__ gamma, const float* __restrict__ beta,
                                  float* __restrict__ scale, float* __restrict__ shift, int N, int C) {
  int f = threadIdx.x;
  if (f >= C) return;
  float mu = sum[f] / (float)N;
  float var = ss[f] / (float)N - mu * mu;
  float sc = gamma[f] * rsqrtf(var + 1e-5f);
  scale[f] = sc;
  shift[f] = beta[f] - mu * sc;
}

// ---------------- final FC with fused BN2 + ELU ----------------
__global__ __launch_bounds__(256) void fc_kernel(const float* __restrict__ x,
                                                 const float* __restrict__ sc, const float* __restrict__ sh,
                                                 const float* __restrict__ W, const float* __restrict__ b,
                                                 float* __restrict__ out, int N) {
  __shared__ float ws[64 * 86];
  __shared__ float xs[32 * 64];
  int tid = threadIdx.x;
  for (int i = tid; i < 64 * 86; i += 256) ws[i] = W[i];
  int n0 = blockIdx.x * 32;
  for (int i = tid; i < 32 * 64; i += 256) {
    int n = n0 + (i >> 6), c = i & 63;
    float v = (n < N) ? x[(size_t)n * 64 + c] : 0.f;
    v = fmaf(v, sc[c], sh[c]);
    xs[i] = v > 0.f ? v : expm1f(v);
  }
  __syncthreads();
  for (int idx = tid; idx < 32 * 86; idx += 256) {
    int nl = idx / 86, o = idx % 86;
    int n = n0 + nl;
    if (n >= N) continue;
    float acc = b[o];
    const float* xr = &xs[nl * 64];
#pragma unroll 8
    for (int k = 0; k < 64; ++k) acc = fmaf(xr[k], ws[k * 86 + o], acc);
    out[(size_t)n * 86 + o] = acc;
  }
}

extern "C" void kernel_launch(void* const* d_in, const int* in_sizes, int n_in,
                              void* d_out, int out_size, void* d_ws, size_t ws_size,
                              hipStream_t stream) {
  const float* x    = (const float*)d_in[0];
  const int*   ei   = (const int*)d_in[1];
  const float* W1   = (const float*)d_in[2];
  const float* asw1 = (const float*)d_in[3];
  const float* adw1 = (const float*)d_in[4];
  const float* b1   = (const float*)d_in[5];
  const float* W2   = (const float*)d_in[6];
  const float* asw2 = (const float*)d_in[7];
  const float* adw2 = (const float*)d_in[8];
  const float* b2   = (const float*)d_in[9];
  const float* g1   = (const float*)d_in[10];
  const float* be1  = (const float*)d_in[11];
  const float* g2   = (const float*)d_in[12];
  const float* be2  = (const float*)d_in[13];
  const float* pw   = (const float*)d_in[14];
  const float* fcW  = (const float*)d_in[15];
  const float* fcb  = (const float*)d_in[16];

  const int N = in_sizes[0] / 256;
  const int E = in_sizes[1] / 2;
  const int EP = E + N;

  char* ws = (char*)d_ws;
  size_t off = 0;
  auto alloc = [&](size_t bytes) {
    char* p = ws + off;
    off += (bytes + 255) & ~(size_t)255;
    return p;
  };
  unsigned short* h    = (unsigned short*)alloc((size_t)N * 256 * 2);  // bf16 hidden
  unsigned short* outb = (unsigned short*)alloc((size_t)N * 256 * 2);  // bf16 layer-1 out
  float* xm   = (float*)alloc((size_t)N * 64 * 4);                     // fp32 layer-2 out (mean)
  float* as1  = (float*)alloc((size_t)N * 4 * 4);
  float* ad1  = (float*)alloc((size_t)N * 4 * 4);
  float* as2  = (float*)alloc((size_t)N * 4 * 4);
  float* ad2  = (float*)alloc((size_t)N * 4 * 4);
  int* rowptr = (int*)alloc((size_t)(N + 1) * 4);
  int* cnt    = (int*)alloc((size_t)N * 4);
  int* cursor = (int*)alloc((size_t)N * 4);
  int* srcs   = (int*)alloc((size_t)EP * 4);
  int* bsums  = (int*)alloc(1024 * 4);
  unsigned short* Wt1 = (unsigned short*)alloc(65536 * 2);
  unsigned short* Wt2 = (unsigned short*)alloc(65536 * 2);
  float* bstat = (float*)alloc(512 * 4);   // sum(256) + ss(256) contiguous
  float* bsum = bstat, *bss = bstat + 256;
  float* bsc  = (float*)alloc(256 * 4);
  float* bsh  = (float*)alloc(256 * 4);
  float* bsc2 = (float*)alloc(64 * 4);
  float* bsh2 = (float*)alloc(64 * 4);

  int egrid = (EP + 255) / 256;
  int ngrid4 = (N + 3) / 4;
  int nb = (N + 255) / 256;
  int ggrid = (N + 127) / 128;

  // CSR build + weight conversion
  hipMemsetAsync(cnt, 0, (size_t)N * 4, stream);
  count_kernel<<<egrid, 256, 0, stream>>>(ei, cnt, E, N);
  convw_kernel<<<512, 256, 0, stream>>>(W1, W2, Wt1, Wt2);
  scan1_kernel<<<nb, 256, 0, stream>>>(cnt, bsums, N);
  scan2_kernel<<<1, 256, 0, stream>>>(bsums, nb);
  scan3_kernel<<<nb, 256, 0, stream>>>(cnt, bsums, rowptr, cursor, N);
  fill_kernel<<<egrid, 256, 0, stream>>>(ei, cursor, srcs, E, N);

  // ---- layer 1 ----
  gemm_kernel<false><<<ggrid, 512, 0, stream>>>(x, Wt1, h, N, nullptr, nullptr, nullptr,
                                                asw1, adw1, as1, ad1);
  agg_kernel<<<ngrid4, 256, 0, stream>>>(h, as1, ad1, rowptr, srcs, b1, outb, nullptr, N, 1);

  hipMemsetAsync(bstat, 0, 512 * 4, stream);
  bnstats_bf16_kernel<<<512, 256, 0, stream>>>(outb, bsum, bss, N);
  bnfinalize_kernel<<<1, 256, 0, stream>>>(bsum, bss, g1, be1, bsc, bsh, N, 256);

  // ---- layer 2 (BN1+PReLU fused into GEMM2 A-staging) ----
  gemm_kernel<true><<<ggrid, 512, 0, stream>>>(outb, Wt2, h, N, bsc, bsh, pw,
                                               asw2, adw2, as2, ad2);
  agg_kernel<<<ngrid4, 256, 0, stream>>>(h, as2, ad2, rowptr, srcs, b2, nullptr, xm, N, 0);

  hipMemsetAsync(bstat, 0, 128 * 4, stream);
  bnstats_kernel<<<512, 256, 0, stream>>>(xm, bstat, bstat + 64, N, 64);
  bnfinalize_kernel<<<1, 64, 0, stream>>>(bstat, bstat + 64, g2, be2, bsc2, bsh2, N, 64);

  // ---- final FC (BN2 + ELU fused) ----
  fc_kernel<<<(N + 31) / 32, 256, 0, stream>>>(xm, bsc2, bsh2, fcW, fcb, (float*)d_out, N);
}

// Round 5
// 586.408 us; speedup vs baseline: 1.8088x; 1.0365x over previous
//
#include <hip/hip_runtime.h>
#include <math.h>

#define LEAKY 0.2f

typedef __attribute__((ext_vector_type(8))) short short8;   // 8 bf16 (4 VGPRs)
typedef __attribute__((ext_vector_type(4))) float f32x4;    // 4 fp32

__device__ __forceinline__ float leaky02(float z) { return z >= 0.f ? z : LEAKY * z; }
__device__ __forceinline__ unsigned short f2bf(float f) {
  unsigned u = __float_as_uint(f);
  unsigned r = u + 0x7fffu + ((u >> 16) & 1u);   // RNE
  return (unsigned short)(r >> 16);
}
__device__ __forceinline__ float bflo(unsigned u) { return __uint_as_float(u << 16); }
__device__ __forceinline__ float bfhi(unsigned u) { return __uint_as_float(u & 0xffff0000u); }

// ---------------- CSR build ----------------
__global__ void count_kernel(const int* __restrict__ ei, int* __restrict__ cnt, int E, int N) {
  int e = blockIdx.x * 256 + threadIdx.x;
  int EP = E + N;
  if (e >= EP) return;
  int d = (e < E) ? ei[E + e] : (e - E);
  atomicAdd(&cnt[d], 1);
}

__global__ __launch_bounds__(256) void scan1_kernel(const int* __restrict__ cnt,
                                                    int* __restrict__ bsums, int n) {
  int i = blockIdx.x * 256 + threadIdx.x;
  int v = (i < n) ? cnt[i] : 0;
  int lane = threadIdx.x & 63, wv = threadIdx.x >> 6;
#pragma unroll
  for (int off = 32; off; off >>= 1) v += __shfl_xor(v, off);
  __shared__ int w[4];
  if (lane == 0) w[wv] = v;
  __syncthreads();
  if (threadIdx.x == 0) bsums[blockIdx.x] = w[0] + w[1] + w[2] + w[3];
}

__global__ __launch_bounds__(256) void scan2_kernel(int* __restrict__ bsums, int nb) {
  int tid = threadIdx.x;
  int lane = tid & 63, wv = tid >> 6;
  int v = (tid < nb) ? bsums[tid] : 0;
  int x = v;
#pragma unroll
  for (int off = 1; off < 64; off <<= 1) {
    int t = __shfl_up(x, off);
    if (lane >= off) x += t;
  }
  __shared__ int ws[4];
  if (lane == 63) ws[wv] = x;
  __syncthreads();
  int woff = 0;
#pragma unroll
  for (int w = 0; w < 4; ++w) if (w < wv) woff += ws[w];
  if (tid < nb) bsums[tid] = x + woff - v;   // exclusive
}

__global__ __launch_bounds__(256) void scan3_kernel(const int* __restrict__ cnt,
                                                    const int* __restrict__ boff,
                                                    int* __restrict__ rowptr,
                                                    int* __restrict__ cursor, int n) {
  int i = blockIdx.x * 256 + threadIdx.x;
  int tid = threadIdx.x, lane = tid & 63, wv = tid >> 6;
  int v = (i < n) ? cnt[i] : 0;
  int x = v;
#pragma unroll
  for (int off = 1; off < 64; off <<= 1) {
    int t = __shfl_up(x, off);
    if (lane >= off) x += t;
  }
  __shared__ int ws[4];
  if (lane == 63) ws[wv] = x;
  __syncthreads();
  int woff = 0;
#pragma unroll
  for (int w = 0; w < 4; ++w) if (w < wv) woff += ws[w];
  int incl = x + woff;
  int base = boff[blockIdx.x];
  if (i < n) {
    rowptr[i + 1] = base + incl;
    cursor[i] = base + incl - v;
  }
  if (i == 0) rowptr[0] = 0;
}

__global__ void fill_kernel(const int* __restrict__ ei, int* __restrict__ cursor,
                            int* __restrict__ srcs, int E, int N) {
  int e = blockIdx.x * 256 + threadIdx.x;
  int EP = E + N;
  if (e >= EP) return;
  int s, d;
  if (e < E) { s = ei[e]; d = ei[E + e]; } else { s = e - E; d = s; }
  int slot = atomicAdd(&cursor[d], 1);
  srcs[slot] = s;
}

// ---------------- converts: W1,W2 -> bf16 transposed; x -> bf16 ----------------
__global__ void convw_kernel(const float* __restrict__ W1, const float* __restrict__ W2,
                             unsigned short* __restrict__ Wt1, unsigned short* __restrict__ Wt2) {
  int idx = blockIdx.x * 256 + threadIdx.x;   // 0..131071
  const float* W;
  unsigned short* Wt;
  if (idx < 65536) { W = W1; Wt = Wt1; } else { W = W2; Wt = Wt2; idx -= 65536; }
  int c = idx >> 8, k = idx & 255;
  Wt[c * 256 + k] = f2bf(W[k * 256 + c]);
}

__global__ void convx_kernel(const float* __restrict__ x, unsigned short* __restrict__ xb,
                             int total) {
  int i = blockIdx.x * 256 + threadIdx.x;
  if (i * 8 >= total) return;
  float4 a = *(const float4*)&x[i * 8];
  float4 b = *(const float4*)&x[i * 8 + 4];
  ushort4 u0, u1;
  u0.x = f2bf(a.x); u0.y = f2bf(a.y); u0.z = f2bf(a.z); u0.w = f2bf(a.w);
  u1.x = f2bf(b.x); u1.y = f2bf(b.y); u1.z = f2bf(b.z); u1.w = f2bf(b.w);
  *(ushort4*)&xb[i * 8] = u0;
  *(ushort4*)&xb[i * 8 + 4] = u1;
}

// ---------------- bf16 MFMA GEMM, 64x256 tile, 4 waves (wave = head) ----------------
// Fused: optional BN+PReLU on A (bf16 in); attention dots as/ad in epilogue.
__global__ __launch_bounds__(256) void gemm_kernel(const unsigned short* __restrict__ Ab,
                                                   const unsigned short* __restrict__ Wt,
                                                   unsigned short* __restrict__ Hout, int M,
                                                   const float* __restrict__ bnsc,
                                                   const float* __restrict__ bnsh,
                                                   const float* __restrict__ pwp,
                                                   const float* __restrict__ att_s,
                                                   const float* __restrict__ att_d,
                                                   float* __restrict__ as_o,
                                                   float* __restrict__ ad_o) {
  __shared__ unsigned short As[64][40];    // +8 pad
  __shared__ unsigned short Bs[256][40];
  int tid = threadIdx.x;
  int bm = blockIdx.x * 64;
  int l = tid & 63, wv = tid >> 6;         // wv = head / 64-col group
  int lr = l & 15, lk = l >> 4;
  f32x4 acc[4][4] = {};
  bool hasbn = (bnsc != nullptr);
  float pws = pwp ? pwp[0] : 0.f;

  for (int k0 = 0; k0 < 256; k0 += 32) {
    // A: 64 rows x 32 k  (512 ushort4)
#pragma unroll
    for (int it = 0; it < 2; ++it) {
      int i = tid + it * 256;
      int row = i >> 3, kk = (i & 7) * 4;
      int gr = bm + row;
      uint2 u = make_uint2(0, 0);
      if (gr < M) u = *(const uint2*)&Ab[(size_t)gr * 256 + k0 + kk];
      if (hasbn) {
        float4 sc = *(const float4*)&bnsc[k0 + kk];
        float4 sh = *(const float4*)&bnsh[k0 + kk];
        float v0 = fmaf(bflo(u.x), sc.x, sh.x);
        float v1 = fmaf(bfhi(u.x), sc.y, sh.y);
        float v2 = fmaf(bflo(u.y), sc.z, sh.z);
        float v3 = fmaf(bfhi(u.y), sc.w, sh.w);
        v0 = v0 >= 0.f ? v0 : v0 * pws; v1 = v1 >= 0.f ? v1 : v1 * pws;
        v2 = v2 >= 0.f ? v2 : v2 * pws; v3 = v3 >= 0.f ? v3 : v3 * pws;
        ushort4 o;
        o.x = f2bf(v0); o.y = f2bf(v1); o.z = f2bf(v2); o.w = f2bf(v3);
        *(ushort4*)&As[row][kk] = o;
      } else {
        *(uint2*)&As[row][kk] = u;
      }
    }
    // B: 256 cols x 32 k  (2048 ushort4)
#pragma unroll
    for (int it = 0; it < 8; ++it) {
      int i = tid + it * 256;
      int c = i >> 3, kk = (i & 7) * 4;
      *(uint2*)&Bs[c][kk] = *(const uint2*)&Wt[(size_t)c * 256 + k0 + kk];
    }
    __syncthreads();
    short8 af[4], bfr[4];
#pragma unroll
    for (int mt = 0; mt < 4; ++mt) af[mt] = *(const short8*)&As[mt * 16 + lr][lk * 8];
#pragma unroll
    for (int nt = 0; nt < 4; ++nt) bfr[nt] = *(const short8*)&Bs[wv * 64 + nt * 16 + lr][lk * 8];
#pragma unroll
    for (int mt = 0; mt < 4; ++mt)
#pragma unroll
      for (int nt = 0; nt < 4; ++nt)
        acc[mt][nt] = __builtin_amdgcn_mfma_f32_16x16x32_bf16(af[mt], bfr[nt], acc[mt][nt], 0, 0, 0);
    __syncthreads();
  }
  // epilogue: C/D map col=lane&15, row=(lane>>4)*4+reg; wave wv owns head wv
  float asv[4], adv[4];
#pragma unroll
  for (int nt = 0; nt < 4; ++nt) {
    int gc = wv * 64 + nt * 16 + lr;
    asv[nt] = att_s[gc];
    adv[nt] = att_d[gc];
  }
#pragma unroll
  for (int mt = 0; mt < 4; ++mt) {
#pragma unroll
    for (int r = 0; r < 4; ++r) {
      int gr = bm + mt * 16 + lk * 4 + r;
      float ps = acc[mt][0][r] * asv[0] + acc[mt][1][r] * asv[1] +
                 acc[mt][2][r] * asv[2] + acc[mt][3][r] * asv[3];
      float pd = acc[mt][0][r] * adv[0] + acc[mt][1][r] * adv[1] +
                 acc[mt][2][r] * adv[2] + acc[mt][3][r] * adv[3];
#pragma unroll
      for (int off = 1; off < 16; off <<= 1) {
        ps += __shfl_xor(ps, off);
        pd += __shfl_xor(pd, off);
      }
      if (lr == 0 && gr < M) {
        as_o[gr * 4 + wv] = ps;
        ad_o[gr * 4 + wv] = pd;
      }
      if (gr < M) {
#pragma unroll
        for (int nt = 0; nt < 4; ++nt)
          Hout[(size_t)gr * 256 + wv * 64 + nt * 16 + lr] = f2bf(acc[mt][nt][r]);
      }
    }
  }
}

// ---------------- GAT aggregation: wave per node; uint4 gather, 2 edges/iter ----------------
__global__ __launch_bounds__(256) void agg_kernel(const unsigned short* __restrict__ h,
                                                  const float* __restrict__ as_,
                                                  const float* __restrict__ ad_,
                                                  const int* __restrict__ rowptr,
                                                  const int* __restrict__ srcs,
                                                  const float* __restrict__ bias,
                                                  unsigned short* __restrict__ out_bf,
                                                  float* __restrict__ out_f,
                                                  int N, int concat) {
  int l = threadIdx.x & 63;
  int n = blockIdx.x * 4 + (threadIdx.x >> 6);
  if (n >= N) return;
  int e0 = rowptr[n], e1 = rowptr[n + 1];
  int deg = e1 - e0;
  int hh = l >> 4, le = l & 15;
  float adh = ad_[n * 4 + hh];

  if (deg <= 64) {
    // softmax: lane (le, hh) owns edges e0+le+16t, head hh
    int sidx[4];
    float lg[4];
#pragma unroll
    for (int t = 0; t < 4; ++t) {
      int j = e0 + le + 16 * t;
      if (j < e1) {
        int s = srcs[j];
        sidx[t] = s;
        lg[t] = leaky02(as_[s * 4 + hh] + adh);
      } else {
        sidx[t] = 0;
        lg[t] = -1e30f;
      }
    }
    float mx = fmaxf(fmaxf(lg[0], lg[1]), fmaxf(lg[2], lg[3]));
#pragma unroll
    for (int off = 1; off < 16; off <<= 1) mx = fmaxf(mx, __shfl_xor(mx, off));
    float ex[4];
    float sm = 0.f;
#pragma unroll
    for (int t = 0; t < 4; ++t) {
      ex[t] = (lg[t] > -1e29f) ? __expf(lg[t] - mx) : 0.f;
      sm += ex[t];
    }
#pragma unroll
    for (int off = 1; off < 16; off <<= 1) sm += __shfl_xor(sm, off);
    float inv = 1.f / (sm + 1e-16f);

    // gather: lane -> parity p=l>>5, m=l&31 owns channels m*8..m*8+7 (head m>>3)
    int p = l >> 5, m = l & 31;
    int hb = m >> 3;
    float invb = __shfl(inv, hb << 4);
    float a[8] = {0.f, 0.f, 0.f, 0.f, 0.f, 0.f, 0.f, 0.f};
#pragma unroll
    for (int t = 0; t < 4; ++t) {
      int base = e0 + 16 * t;
      if (base >= e1) break;
      int cntc = min(16, e1 - base);
      int npr = (cntc + 1) >> 1;
      for (int pr = 0; pr < npr; ++pr) {
        int q = 2 * pr + p;
        int s = __shfl(sidx[t], q);
        float al = __shfl(ex[t], q + (hb << 4)) * invb;
        uint4 hv = *(const uint4*)&h[(size_t)s * 256 + m * 8];
        a[0] = fmaf(bflo(hv.x), al, a[0]);
        a[1] = fmaf(bfhi(hv.x), al, a[1]);
        a[2] = fmaf(bflo(hv.y), al, a[2]);
        a[3] = fmaf(bfhi(hv.y), al, a[3]);
        a[4] = fmaf(bflo(hv.z), al, a[4]);
        a[5] = fmaf(bfhi(hv.z), al, a[5]);
        a[6] = fmaf(bflo(hv.w), al, a[6]);
        a[7] = fmaf(bfhi(hv.w), al, a[7]);
      }
    }
    // combine parities: lanes l and l^32 share channels
#pragma unroll
    for (int i = 0; i < 8; ++i) a[i] += __shfl_xor(a[i], 32);
    if (concat) {
      if (l < 32) {
        float4 b0 = *(const float4*)&bias[m * 8];
        float4 b1 = *(const float4*)&bias[m * 8 + 4];
        ushort4 o0, o1;
        o0.x = f2bf(a[0] + b0.x); o0.y = f2bf(a[1] + b0.y);
        o0.z = f2bf(a[2] + b0.z); o0.w = f2bf(a[3] + b0.w);
        o1.x = f2bf(a[4] + b1.x); o1.y = f2bf(a[5] + b1.y);
        o1.z = f2bf(a[6] + b1.z); o1.w = f2bf(a[7] + b1.w);
        *(ushort4*)&out_bf[(size_t)n * 256 + m * 8] = o0;
        *(ushort4*)&out_bf[(size_t)n * 256 + m * 8 + 4] = o1;
      }
    } else {
      // mean over heads: sum lanes m, m+8, m+16, m+24
#pragma unroll
      for (int i = 0; i < 8; ++i) {
        a[i] += __shfl_xor(a[i], 8);
        a[i] += __shfl_xor(a[i], 16);
      }
      if (l < 8) {
        float4 b0 = *(const float4*)&bias[m * 8];
        float4 b1 = *(const float4*)&bias[m * 8 + 4];
        float4 o0 = make_float4(0.25f * a[0] + b0.x, 0.25f * a[1] + b0.y,
                                0.25f * a[2] + b0.z, 0.25f * a[3] + b0.w);
        float4 o1 = make_float4(0.25f * a[4] + b1.x, 0.25f * a[5] + b1.y,
                                0.25f * a[6] + b1.z, 0.25f * a[7] + b1.w);
        *(float4*)&out_f[(size_t)n * 64 + m * 8] = o0;
        *(float4*)&out_f[(size_t)n * 64 + m * 8 + 4] = o1;
      }
    }
  } else {
    // general fallback (deg > 64): strided phases + per-edge exp, 4 ch/lane
    float ad4[4] = {ad_[n * 4], ad_[n * 4 + 1], ad_[n * 4 + 2], ad_[n * 4 + 3]};
    float mx[4] = {-1e30f, -1e30f, -1e30f, -1e30f};
    for (int j = e0 + l; j < e1; j += 64) {
      int s = srcs[j];
      float4 av = *(const float4*)&as_[s * 4];
      mx[0] = fmaxf(mx[0], leaky02(av.x + ad4[0]));
      mx[1] = fmaxf(mx[1], leaky02(av.y + ad4[1]));
      mx[2] = fmaxf(mx[2], leaky02(av.z + ad4[2]));
      mx[3] = fmaxf(mx[3], leaky02(av.w + ad4[3]));
    }
#pragma unroll
    for (int off = 32; off; off >>= 1) {
      mx[0] = fmaxf(mx[0], __shfl_xor(mx[0], off));
      mx[1] = fmaxf(mx[1], __shfl_xor(mx[1], off));
      mx[2] = fmaxf(mx[2], __shfl_xor(mx[2], off));
      mx[3] = fmaxf(mx[3], __shfl_xor(mx[3], off));
    }
    float sm[4] = {0.f, 0.f, 0.f, 0.f};
    for (int j = e0 + l; j < e1; j += 64) {
      int s = srcs[j];
      float4 av = *(const float4*)&as_[s * 4];
      sm[0] += __expf(leaky02(av.x + ad4[0]) - mx[0]);
      sm[1] += __expf(leaky02(av.y + ad4[1]) - mx[1]);
      sm[2] += __expf(leaky02(av.z + ad4[2]) - mx[2]);
      sm[3] += __expf(leaky02(av.w + ad4[3]) - mx[3]);
    }
#pragma unroll
    for (int off = 32; off; off >>= 1) {
      sm[0] += __shfl_xor(sm[0], off);
      sm[1] += __shfl_xor(sm[1], off);
      sm[2] += __shfl_xor(sm[2], off);
      sm[3] += __shfl_xor(sm[3], off);
    }
    float mh = hh == 0 ? mx[0] : hh == 1 ? mx[1] : hh == 2 ? mx[2] : mx[3];
    float sh = hh == 0 ? sm[0] : hh == 1 ? sm[1] : hh == 2 ? sm[2] : sm[3];
    float inv = 1.f / (sh + 1e-16f);
    float a0 = 0.f, a1 = 0.f, a2 = 0.f, a3 = 0.f;
    for (int j = e0; j < e1; ++j) {
      int s = srcs[j];
      float al = __expf(leaky02(as_[s * 4 + hh] + adh) - mh) * inv;
      uint2 hv = *(const uint2*)&h[(size_t)s * 256 + l * 4];
      a0 = fmaf(bflo(hv.x), al, a0); a1 = fmaf(bfhi(hv.x), al, a1);
      a2 = fmaf(bflo(hv.y), al, a2); a3 = fmaf(bfhi(hv.y), al, a3);
    }
    if (concat) {
      float4 b4 = *(const float4*)&bias[l * 4];
      ushort4 o;
      o.x = f2bf(a0 + b4.x); o.y = f2bf(a1 + b4.y);
      o.z = f2bf(a2 + b4.z); o.w = f2bf(a3 + b4.w);
      *(ushort4*)&out_bf[(size_t)n * 256 + l * 4] = o;
    } else {
      a0 += __shfl_xor(a0, 16); a0 += __shfl_xor(a0, 32);
      a1 += __shfl_xor(a1, 16); a1 += __shfl_xor(a1, 32);
      a2 += __shfl_xor(a2, 16); a2 += __shfl_xor(a2, 32);
      a3 += __shfl_xor(a3, 16); a3 += __shfl_xor(a3, 32);
      if (l < 16) {
        float4 b4 = *(const float4*)&bias[l * 4];
        float4 o = make_float4(0.25f * a0 + b4.x, 0.25f * a1 + b4.y,
                               0.25f * a2 + b4.z, 0.25f * a3 + b4.w);
        *(float4*)&out_f[(size_t)n * 64 + l * 4] = o;
      }
    }
  }
}

// ---------------- BatchNorm stats ----------------
__global__ __launch_bounds__(256) void bnstats_bf16_kernel(const unsigned short* __restrict__ x,
                                                           float* __restrict__ sum,
                                                           float* __restrict__ ss, int N) {
  int tid = threadIdx.x;
  int c = (tid & 127) * 2;
  int r = blockIdx.x * 2 + (tid >> 7);
  int stride = gridDim.x * 2;
  float a0 = 0.f, b0 = 0.f, a1 = 0.f, b1 = 0.f;
  for (; r < N; r += stride) {
    unsigned u = *(const unsigned*)&x[(size_t)r * 256 + c];
    float v0 = bflo(u), v1 = bfhi(u);
    a0 += v0; b0 += v0 * v0;
    a1 += v1; b1 += v1 * v1;
  }
  atomicAdd(&sum[c], a0); atomicAdd(&ss[c], b0);
  atomicAdd(&sum[c + 1], a1); atomicAdd(&ss[c + 1], b1);
}

__global__ __launch_bounds__(256) void bnstats_kernel(const float* __restrict__ x,
                                                      float* __restrict__ sum, float* __restrict__ ss,
                                                      int N, int C) {
  int tid = threadIdx.x;
  int f = tid % C;
  int rpb = 256 / C;
  int r = blockIdx.x * rpb + tid / C;
  int stride = gridDim.x * rpb;
  float a = 0.f, b = 0.f;
  for (; r < N; r += stride) {
    float v = x[(size_t)r * C + f];
    a += v;
    b += v * v;
  }
  atomicAdd(&sum[f], a);
  atomicAdd(&ss[f], b);
}

__global__ void bnfinalize_kernel(const float* __restrict__ sum, const float* __restrict__ ss,
                                  const float* __restrict__ gamma, const float* __restrict__ beta,
                                  float* __restrict__ scale, float* __restrict__ shift, int N, int C) {
  int f = threadIdx.x;
  if (f >= C) return;
  float mu = sum[f] / (float)N;
  float var = ss[f] / (float)N - mu * mu;
  float sc = gamma[f] * rsqrtf(var + 1e-5f);
  scale[f] = sc;
  shift[f] = beta[f] - mu * sc;
}

// ---------------- final FC with fused BN2 + ELU ----------------
__global__ __launch_bounds__(256) void fc_kernel(const float* __restrict__ x,
                                                 const float* __restrict__ sc, const float* __restrict__ sh,
                                                 const float* __restrict__ W, const float* __restrict__ b,
                                                 float* __restrict__ out, int N) {
  __shared__ float ws[64 * 86];
  __shared__ float xs[32 * 64];
  int tid = threadIdx.x;
  for (int i = tid; i < 64 * 86; i += 256) ws[i] = W[i];
  int n0 = blockIdx.x * 32;
  for (int i = tid; i < 32 * 64; i += 256) {
    int n = n0 + (i >> 6), c = i & 63;
    float v = (n < N) ? x[(size_t)n * 64 + c] : 0.f;
    v = fmaf(v, sc[c], sh[c]);
    xs[i] = v > 0.f ? v : expm1f(v);
  }
  __syncthreads();
  for (int idx = tid; idx < 32 * 86; idx += 256) {
    int nl = idx / 86, o = idx % 86;
    int n = n0 + nl;
    if (n >= N) continue;
    float acc = b[o];
    const float* xr = &xs[nl * 64];
#pragma unroll 8
    for (int k = 0; k < 64; ++k) acc = fmaf(xr[k], ws[k * 86 + o], acc);
    out[(size_t)n * 86 + o] = acc;
  }
}

extern "C" void kernel_launch(void* const* d_in, const int* in_sizes, int n_in,
                              void* d_out, int out_size, void* d_ws, size_t ws_size,
                              hipStream_t stream) {
  const float* x    = (const float*)d_in[0];
  const int*   ei   = (const int*)d_in[1];
  const float* W1   = (const float*)d_in[2];
  const float* asw1 = (const float*)d_in[3];
  const float* adw1 = (const float*)d_in[4];
  const float* b1   = (const float*)d_in[5];
  const float* W2   = (const float*)d_in[6];
  const float* asw2 = (const float*)d_in[7];
  const float* adw2 = (const float*)d_in[8];
  const float* b2   = (const float*)d_in[9];
  const float* g1   = (const float*)d_in[10];
  const float* be1  = (const float*)d_in[11];
  const float* g2   = (const float*)d_in[12];
  const float* be2  = (const float*)d_in[13];
  const float* pw   = (const float*)d_in[14];
  const float* fcW  = (const float*)d_in[15];
  const float* fcb  = (const float*)d_in[16];

  const int N = in_sizes[0] / 256;
  const int E = in_sizes[1] / 2;
  const int EP = E + N;

  char* ws = (char*)d_ws;
  size_t off = 0;
  auto alloc = [&](size_t bytes) {
    char* p = ws + off;
    off += (bytes + 255) & ~(size_t)255;
    return p;
  };
  unsigned short* xb   = (unsigned short*)alloc((size_t)N * 256 * 2);  // bf16 input
  unsigned short* h    = (unsigned short*)alloc((size_t)N * 256 * 2);  // bf16 hidden
  unsigned short* outb = (unsigned short*)alloc((size_t)N * 256 * 2);  // bf16 layer-1 out
  float* xm   = (float*)alloc((size_t)N * 64 * 4);                     // fp32 layer-2 out (mean)
  float* as1  = (float*)alloc((size_t)N * 4 * 4);
  float* ad1  = (float*)alloc((size_t)N * 4 * 4);
  float* as2  = (float*)alloc((size_t)N * 4 * 4);
  float* ad2  = (float*)alloc((size_t)N * 4 * 4);
  int* rowptr = (int*)alloc((size_t)(N + 1) * 4);
  int* cnt    = (int*)alloc((size_t)N * 4);
  int* cursor = (int*)alloc((size_t)N * 4);
  int* srcs   = (int*)alloc((size_t)EP * 4);
  int* bsums  = (int*)alloc(1024 * 4);
  unsigned short* Wt1 = (unsigned short*)alloc(65536 * 2);
  unsigned short* Wt2 = (unsigned short*)alloc(65536 * 2);
  float* bstat = (float*)alloc(512 * 4);   // sum(256) + ss(256)
  float* bsum = bstat, *bss = bstat + 256;
  float* bsc  = (float*)alloc(256 * 4);
  float* bsh  = (float*)alloc(256 * 4);
  float* bsc2 = (float*)alloc(64 * 4);
  float* bsh2 = (float*)alloc(64 * 4);

  int egrid = (EP + 255) / 256;
  int ngrid4 = (N + 3) / 4;
  int nb = (N + 255) / 256;
  int ggrid = (N + 63) / 64;

  // CSR build + conversions
  hipMemsetAsync(cnt, 0, (size_t)N * 4, stream);
  count_kernel<<<egrid, 256, 0, stream>>>(ei, cnt, E, N);
  convw_kernel<<<512, 256, 0, stream>>>(W1, W2, Wt1, Wt2);
  convx_kernel<<<(N * 32 + 255) / 256, 256, 0, stream>>>(x, xb, N * 256);
  scan1_kernel<<<nb, 256, 0, stream>>>(cnt, bsums, N);
  scan2_kernel<<<1, 256, 0, stream>>>(bsums, nb);
  scan3_kernel<<<nb, 256, 0, stream>>>(cnt, bsums, rowptr, cursor, N);
  fill_kernel<<<egrid, 256, 0, stream>>>(ei, cursor, srcs, E, N);

  // ---- layer 1 ----
  gemm_kernel<<<ggrid, 256, 0, stream>>>(xb, Wt1, h, N, nullptr, nullptr, nullptr,
                                         asw1, adw1, as1, ad1);
  agg_kernel<<<ngrid4, 256, 0, stream>>>(h, as1, ad1, rowptr, srcs, b1, outb, nullptr, N, 1);

  hipMemsetAsync(bstat, 0, 512 * 4, stream);
  bnstats_bf16_kernel<<<512, 256, 0, stream>>>(outb, bsum, bss, N);
  bnfinalize_kernel<<<1, 256, 0, stream>>>(bsum, bss, g1, be1, bsc, bsh, N, 256);

  // ---- layer 2 (BN1+PReLU fused into GEMM2 A-staging) ----
  gemm_kernel<<<ggrid, 256, 0, stream>>>(outb, Wt2, h, N, bsc, bsh, pw,
                                         asw2, adw2, as2, ad2);
  agg_kernel<<<ngrid4, 256, 0, stream>>>(h, as2, ad2, rowptr, srcs, b2, nullptr, xm, N, 0);

  hipMemsetAsync(bstat, 0, 128 * 4, stream);
  bnstats_kernel<<<512, 256, 0, stream>>>(xm, bstat, bstat + 64, N, 64);
  bnfinalize_kernel<<<1, 64, 0, stream>>>(bstat, bstat + 64, g2, be2, bsc2, bsh2, N, 64);

  // ---- final FC (BN2 + ELU fused) ----
  fc_kernel<<<(N + 31) / 32, 256, 0, stream>>>(xm, bsc2, bsh2, fcW, fcb, (float*)d_out, N);
}

// Round 6
// 565.842 us; speedup vs baseline: 1.8746x; 1.0363x over previous
//
#include <hip/hip_runtime.h>
#include <math.h>

#define LEAKY 0.2f

typedef __attribute__((ext_vector_type(8))) short short8;   // 8 bf16 (4 VGPRs)
typedef __attribute__((ext_vector_type(4))) float f32x4;    // 4 fp32

__device__ __forceinline__ float leaky02(float z) { return z >= 0.f ? z : LEAKY * z; }
__device__ __forceinline__ unsigned short f2bf(float f) {
  unsigned u = __float_as_uint(f);
  unsigned r = u + 0x7fffu + ((u >> 16) & 1u);   // RNE
  return (unsigned short)(r >> 16);
}
__device__ __forceinline__ float bflo(unsigned u) { return __uint_as_float(u << 16); }
__device__ __forceinline__ float bfhi(unsigned u) { return __uint_as_float(u & 0xffff0000u); }

// ---------------- CSR build ----------------
__global__ void count_kernel(const int* __restrict__ ei, int* __restrict__ cnt, int E, int N) {
  int e = blockIdx.x * 256 + threadIdx.x;
  int EP = E + N;
  if (e >= EP) return;
  int d = (e < E) ? ei[E + e] : (e - E);
  atomicAdd(&cnt[d], 1);
}

__global__ __launch_bounds__(256) void scan1_kernel(const int* __restrict__ cnt,
                                                    int* __restrict__ bsums, int n) {
  int i = blockIdx.x * 256 + threadIdx.x;
  int v = (i < n) ? cnt[i] : 0;
  int lane = threadIdx.x & 63, wv = threadIdx.x >> 6;
#pragma unroll
  for (int off = 32; off; off >>= 1) v += __shfl_xor(v, off);
  __shared__ int w[4];
  if (lane == 0) w[wv] = v;
  __syncthreads();
  if (threadIdx.x == 0) bsums[blockIdx.x] = w[0] + w[1] + w[2] + w[3];
}

__global__ __launch_bounds__(256) void scan2_kernel(int* __restrict__ bsums, int nb) {
  int tid = threadIdx.x;
  int lane = tid & 63, wv = tid >> 6;
  int v = (tid < nb) ? bsums[tid] : 0;
  int x = v;
#pragma unroll
  for (int off = 1; off < 64; off <<= 1) {
    int t = __shfl_up(x, off);
    if (lane >= off) x += t;
  }
  __shared__ int ws[4];
  if (lane == 63) ws[wv] = x;
  __syncthreads();
  int woff = 0;
#pragma unroll
  for (int w = 0; w < 4; ++w) if (w < wv) woff += ws[w];
  if (tid < nb) bsums[tid] = x + woff - v;   // exclusive
}

__global__ __launch_bounds__(256) void scan3_kernel(const int* __restrict__ cnt,
                                                    const int* __restrict__ boff,
                                                    int* __restrict__ rowptr,
                                                    int* __restrict__ cursor, int n) {
  int i = blockIdx.x * 256 + threadIdx.x;
  int tid = threadIdx.x, lane = tid & 63, wv = tid >> 6;
  int v = (i < n) ? cnt[i] : 0;
  int x = v;
#pragma unroll
  for (int off = 1; off < 64; off <<= 1) {
    int t = __shfl_up(x, off);
    if (lane >= off) x += t;
  }
  __shared__ int ws[4];
  if (lane == 63) ws[wv] = x;
  __syncthreads();
  int woff = 0;
#pragma unroll
  for (int w = 0; w < 4; ++w) if (w < wv) woff += ws[w];
  int incl = x + woff;
  int base = boff[blockIdx.x];
  if (i < n) {
    rowptr[i + 1] = base + incl;
    cursor[i] = base + incl - v;
  }
  if (i == 0) rowptr[0] = 0;
}

__global__ void fill_kernel(const int* __restrict__ ei, int* __restrict__ cursor,
                            int* __restrict__ srcs, int E, int N) {
  int e = blockIdx.x * 256 + threadIdx.x;
  int EP = E + N;
  if (e >= EP) return;
  int s, d;
  if (e < E) { s = ei[e]; d = ei[E + e]; } else { s = e - E; d = s; }
  int slot = atomicAdd(&cursor[d], 1);
  srcs[slot] = s;
}

// ---------------- weight convert: Wt[c][k] = bf16(W[k][c]) ----------------
__global__ void convw_kernel(const float* __restrict__ W1, const float* __restrict__ W2,
                             unsigned short* __restrict__ Wt1, unsigned short* __restrict__ Wt2) {
  int idx = blockIdx.x * 256 + threadIdx.x;   // 0..131071
  const float* W;
  unsigned short* Wt;
  if (idx < 65536) { W = W1; Wt = Wt1; } else { W = W2; Wt = Wt2; idx -= 65536; }
  int c = idx >> 8, k = idx & 255;
  Wt[c * 256 + k] = f2bf(W[k * 256 + c]);
}

// ---------------- bf16 MFMA GEMM, 128x256 tile, 8 waves (2m x 4n) ----------------
// A loader: fp32 (BF16A=false) or bf16 (+optional BN+PReLU). Fused attention dots.
template <bool BF16A>
__global__ __launch_bounds__(512) void gemm_kernel(const void* __restrict__ Av,
                                                   const unsigned short* __restrict__ Wt,
                                                   unsigned short* __restrict__ Hout, int M,
                                                   const float* __restrict__ bnsc,
                                                   const float* __restrict__ bnsh,
                                                   const float* __restrict__ pwp,
                                                   const float* __restrict__ att_s,
                                                   const float* __restrict__ att_d,
                                                   float* __restrict__ as_o,
                                                   float* __restrict__ ad_o) {
  __shared__ unsigned short As[128][40];    // +8 pad
  __shared__ unsigned short Bs[256][40];
  int tid = threadIdx.x;
  int bm = blockIdx.x * 128;
  int l = tid & 63, wv = tid >> 6;
  int wm = wv >> 2, wn = wv & 3;            // 2 x 4 waves; wave tile 64 rows x 64 cols
  int lr = l & 15, lk = l >> 4;
  f32x4 acc[4][4] = {};
  bool hasbn = (bnsc != nullptr);
  float pws = pwp ? pwp[0] : 0.f;

  for (int k0 = 0; k0 < 256; k0 += 32) {
    // A: 128 rows x 32 k = 4096 bf16 -> 512 threads x 8 elems
    {
      int row = tid >> 2, kq = (tid & 3) * 8;
      int gr = bm + row;
      if (BF16A) {
        uint4 u = make_uint4(0, 0, 0, 0);
        if (gr < M) u = *(const uint4*)((const unsigned short*)Av + (size_t)gr * 256 + k0 + kq);
        if (hasbn) {
          float4 sc0 = *(const float4*)&bnsc[k0 + kq];
          float4 sh0 = *(const float4*)&bnsh[k0 + kq];
          float4 sc1 = *(const float4*)&bnsc[k0 + kq + 4];
          float4 sh1 = *(const float4*)&bnsh[k0 + kq + 4];
          float v0 = fmaf(bflo(u.x), sc0.x, sh0.x);
          float v1 = fmaf(bfhi(u.x), sc0.y, sh0.y);
          float v2 = fmaf(bflo(u.y), sc0.z, sh0.z);
          float v3 = fmaf(bfhi(u.y), sc0.w, sh0.w);
          float v4 = fmaf(bflo(u.z), sc1.x, sh1.x);
          float v5 = fmaf(bfhi(u.z), sc1.y, sh1.y);
          float v6 = fmaf(bflo(u.w), sc1.z, sh1.z);
          float v7 = fmaf(bfhi(u.w), sc1.w, sh1.w);
          v0 = v0 >= 0.f ? v0 : v0 * pws; v1 = v1 >= 0.f ? v1 : v1 * pws;
          v2 = v2 >= 0.f ? v2 : v2 * pws; v3 = v3 >= 0.f ? v3 : v3 * pws;
          v4 = v4 >= 0.f ? v4 : v4 * pws; v5 = v5 >= 0.f ? v5 : v5 * pws;
          v6 = v6 >= 0.f ? v6 : v6 * pws; v7 = v7 >= 0.f ? v7 : v7 * pws;
          ushort4 o0, o1;
          o0.x = f2bf(v0); o0.y = f2bf(v1); o0.z = f2bf(v2); o0.w = f2bf(v3);
          o1.x = f2bf(v4); o1.y = f2bf(v5); o1.z = f2bf(v6); o1.w = f2bf(v7);
          *(ushort4*)&As[row][kq] = o0;
          *(ushort4*)&As[row][kq + 4] = o1;
        } else {
          *(uint4*)&As[row][kq] = u;
        }
      } else {
        float4 a0 = make_float4(0.f, 0.f, 0.f, 0.f), a1 = a0;
        if (gr < M) {
          a0 = *(const float4*)((const float*)Av + (size_t)gr * 256 + k0 + kq);
          a1 = *(const float4*)((const float*)Av + (size_t)gr * 256 + k0 + kq + 4);
        }
        ushort4 o0, o1;
        o0.x = f2bf(a0.x); o0.y = f2bf(a0.y); o0.z = f2bf(a0.z); o0.w = f2bf(a0.w);
        o1.x = f2bf(a1.x); o1.y = f2bf(a1.y); o1.z = f2bf(a1.z); o1.w = f2bf(a1.w);
        *(ushort4*)&As[row][kq] = o0;
        *(ushort4*)&As[row][kq + 4] = o1;
      }
    }
    // B: 256 cols x 32 k = 8192 bf16 -> 512 threads x 16 elems (2 uint4)
#pragma unroll
    for (int it = 0; it < 2; ++it) {
      int i = tid + it * 512;
      int c = i >> 2, kq = (i & 3) * 8;
      *(uint4*)&Bs[c][kq] = *(const uint4*)&Wt[(size_t)c * 256 + k0 + kq];
    }
    __syncthreads();
    short8 af[4], bfr[4];
#pragma unroll
    for (int mt = 0; mt < 4; ++mt) af[mt] = *(const short8*)&As[wm * 64 + mt * 16 + lr][lk * 8];
#pragma unroll
    for (int nt = 0; nt < 4; ++nt) bfr[nt] = *(const short8*)&Bs[wn * 64 + nt * 16 + lr][lk * 8];
#pragma unroll
    for (int mt = 0; mt < 4; ++mt)
#pragma unroll
      for (int nt = 0; nt < 4; ++nt)
        acc[mt][nt] = __builtin_amdgcn_mfma_f32_16x16x32_bf16(af[mt], bfr[nt], acc[mt][nt], 0, 0, 0);
    __syncthreads();
  }
  // epilogue: C/D map col=lane&15, row=(lane>>4)*4+reg; wave (wm,wn): rows wm*64+, head wn
  float asv[4], adv[4];
#pragma unroll
  for (int nt = 0; nt < 4; ++nt) {
    int gc = wn * 64 + nt * 16 + lr;
    asv[nt] = att_s[gc];
    adv[nt] = att_d[gc];
  }
#pragma unroll
  for (int mt = 0; mt < 4; ++mt) {
#pragma unroll
    for (int r = 0; r < 4; ++r) {
      int gr = bm + wm * 64 + mt * 16 + lk * 4 + r;
      float ps = acc[mt][0][r] * asv[0] + acc[mt][1][r] * asv[1] +
                 acc[mt][2][r] * asv[2] + acc[mt][3][r] * asv[3];
      float pd = acc[mt][0][r] * adv[0] + acc[mt][1][r] * adv[1] +
                 acc[mt][2][r] * adv[2] + acc[mt][3][r] * adv[3];
#pragma unroll
      for (int off = 1; off < 16; off <<= 1) {
        ps += __shfl_xor(ps, off);
        pd += __shfl_xor(pd, off);
      }
      if (lr == 0 && gr < M) {
        as_o[gr * 4 + wn] = ps;
        ad_o[gr * 4 + wn] = pd;
      }
      if (gr < M) {
#pragma unroll
        for (int nt = 0; nt < 4; ++nt)
          Hout[(size_t)gr * 256 + wn * 64 + nt * 16 + lr] = f2bf(acc[mt][nt][r]);
      }
    }
  }
}

// ---------------- GAT aggregation: wave per node; uint4 gather, 2 edges/iter ----------------
__global__ __launch_bounds__(256) void agg_kernel(const unsigned short* __restrict__ h,
                                                  const float* __restrict__ as_,
                                                  const float* __restrict__ ad_,
                                                  const int* __restrict__ rowptr,
                                                  const int* __restrict__ srcs,
                                                  const float* __restrict__ bias,
                                                  unsigned short* __restrict__ out_bf,
                                                  float* __restrict__ out_f,
                                                  int N, int concat) {
  int l = threadIdx.x & 63;
  int n = blockIdx.x * 4 + (threadIdx.x >> 6);
  if (n >= N) return;
  int e0 = rowptr[n], e1 = rowptr[n + 1];
  int deg = e1 - e0;
  int hh = l >> 4, le = l & 15;
  float adh = ad_[n * 4 + hh];

  if (deg <= 64) {
    int sidx[4];
    float lg[4];
#pragma unroll
    for (int t = 0; t < 4; ++t) {
      int j = e0 + le + 16 * t;
      if (j < e1) {
        int s = srcs[j];
        sidx[t] = s;
        lg[t] = leaky02(as_[s * 4 + hh] + adh);
      } else {
        sidx[t] = 0;
        lg[t] = -1e30f;
      }
    }
    float mx = fmaxf(fmaxf(lg[0], lg[1]), fmaxf(lg[2], lg[3]));
#pragma unroll
    for (int off = 1; off < 16; off <<= 1) mx = fmaxf(mx, __shfl_xor(mx, off));
    float ex[4];
    float sm = 0.f;
#pragma unroll
    for (int t = 0; t < 4; ++t) {
      ex[t] = (lg[t] > -1e29f) ? __expf(lg[t] - mx) : 0.f;
      sm += ex[t];
    }
#pragma unroll
    for (int off = 1; off < 16; off <<= 1) sm += __shfl_xor(sm, off);
    float inv = 1.f / (sm + 1e-16f);

    int p = l >> 5, m = l & 31;
    int hb = m >> 3;
    float invb = __shfl(inv, hb << 4);
    float a[8] = {0.f, 0.f, 0.f, 0.f, 0.f, 0.f, 0.f, 0.f};
#pragma unroll
    for (int t = 0; t < 4; ++t) {
      int base = e0 + 16 * t;
      if (base >= e1) break;
      int cntc = min(16, e1 - base);
      int npr = (cntc + 1) >> 1;
      for (int pr = 0; pr < npr; ++pr) {
        int q = 2 * pr + p;
        int s = __shfl(sidx[t], q);
        float al = __shfl(ex[t], q + (hb << 4)) * invb;
        uint4 hv = *(const uint4*)&h[(size_t)s * 256 + m * 8];
        a[0] = fmaf(bflo(hv.x), al, a[0]);
        a[1] = fmaf(bfhi(hv.x), al, a[1]);
        a[2] = fmaf(bflo(hv.y), al, a[2]);
        a[3] = fmaf(bfhi(hv.y), al, a[3]);
        a[4] = fmaf(bflo(hv.z), al, a[4]);
        a[5] = fmaf(bfhi(hv.z), al, a[5]);
        a[6] = fmaf(bflo(hv.w), al, a[6]);
        a[7] = fmaf(bfhi(hv.w), al, a[7]);
      }
    }
#pragma unroll
    for (int i = 0; i < 8; ++i) a[i] += __shfl_xor(a[i], 32);
    if (concat) {
      if (l < 32) {
        float4 b0 = *(const float4*)&bias[m * 8];
        float4 b1 = *(const float4*)&bias[m * 8 + 4];
        ushort4 o0, o1;
        o0.x = f2bf(a[0] + b0.x); o0.y = f2bf(a[1] + b0.y);
        o0.z = f2bf(a[2] + b0.z); o0.w = f2bf(a[3] + b0.w);
        o1.x = f2bf(a[4] + b1.x); o1.y = f2bf(a[5] + b1.y);
        o1.z = f2bf(a[6] + b1.z); o1.w = f2bf(a[7] + b1.w);
        *(ushort4*)&out_bf[(size_t)n * 256 + m * 8] = o0;
        *(ushort4*)&out_bf[(size_t)n * 256 + m * 8 + 4] = o1;
      }
    } else {
#pragma unroll
      for (int i = 0; i < 8; ++i) {
        a[i] += __shfl_xor(a[i], 8);
        a[i] += __shfl_xor(a[i], 16);
      }
      if (l < 8) {
        float4 b0 = *(const float4*)&bias[m * 8];
        float4 b1 = *(const float4*)&bias[m * 8 + 4];
        float4 o0 = make_float4(0.25f * a[0] + b0.x, 0.25f * a[1] + b0.y,
                                0.25f * a[2] + b0.z, 0.25f * a[3] + b0.w);
        float4 o1 = make_float4(0.25f * a[4] + b1.x, 0.25f * a[5] + b1.y,
                                0.25f * a[6] + b1.z, 0.25f * a[7] + b1.w);
        *(float4*)&out_f[(size_t)n * 64 + m * 8] = o0;
        *(float4*)&out_f[(size_t)n * 64 + m * 8 + 4] = o1;
      }
    }
  } else {
    float ad4[4] = {ad_[n * 4], ad_[n * 4 + 1], ad_[n * 4 + 2], ad_[n * 4 + 3]};
    float mx[4] = {-1e30f, -1e30f, -1e30f, -1e30f};
    for (int j = e0 + l; j < e1; j += 64) {
      int s = srcs[j];
      float4 av = *(const float4*)&as_[s * 4];
      mx[0] = fmaxf(mx[0], leaky02(av.x + ad4[0]));
      mx[1] = fmaxf(mx[1], leaky02(av.y + ad4[1]));
      mx[2] = fmaxf(mx[2], leaky02(av.z + ad4[2]));
      mx[3] = fmaxf(mx[3], leaky02(av.w + ad4[3]));
    }
#pragma unroll
    for (int off = 32; off; off >>= 1) {
      mx[0] = fmaxf(mx[0], __shfl_xor(mx[0], off));
      mx[1] = fmaxf(mx[1], __shfl_xor(mx[1], off));
      mx[2] = fmaxf(mx[2], __shfl_xor(mx[2], off));
      mx[3] = fmaxf(mx[3], __shfl_xor(mx[3], off));
    }
    float sm[4] = {0.f, 0.f, 0.f, 0.f};
    for (int j = e0 + l; j < e1; j += 64) {
      int s = srcs[j];
      float4 av = *(const float4*)&as_[s * 4];
      sm[0] += __expf(leaky02(av.x + ad4[0]) - mx[0]);
      sm[1] += __expf(leaky02(av.y + ad4[1]) - mx[1]);
      sm[2] += __expf(leaky02(av.z + ad4[2]) - mx[2]);
      sm[3] += __expf(leaky02(av.w + ad4[3]) - mx[3]);
    }
#pragma unroll
    for (int off = 32; off; off >>= 1) {
      sm[0] += __shfl_xor(sm[0], off);
      sm[1] += __shfl_xor(sm[1], off);
      sm[2] += __shfl_xor(sm[2], off);
      sm[3] += __shfl_xor(sm[3], off);
    }
    float mh = hh == 0 ? mx[0] : hh == 1 ? mx[1] : hh == 2 ? mx[2] : mx[3];
    float sh = hh == 0 ? sm[0] : hh == 1 ? sm[1] : hh == 2 ? sm[2] : sm[3];
    float inv = 1.f / (sh + 1e-16f);
    float a0 = 0.f, a1 = 0.f, a2 = 0.f, a3 = 0.f;
    for (int j = e0; j < e1; ++j) {
      int s = srcs[j];
      float al = __expf(leaky02(as_[s * 4 + hh] + adh) - mh) * inv;
      uint2 hv = *(const uint2*)&h[(size_t)s * 256 + l * 4];
      a0 = fmaf(bflo(hv.x), al, a0); a1 = fmaf(bfhi(hv.x), al, a1);
      a2 = fmaf(bflo(hv.y), al, a2); a3 = fmaf(bfhi(hv.y), al, a3);
    }
    if (concat) {
      float4 b4 = *(const float4*)&bias[l * 4];
      ushort4 o;
      o.x = f2bf(a0 + b4.x); o.y = f2bf(a1 + b4.y);
      o.z = f2bf(a2 + b4.z); o.w = f2bf(a3 + b4.w);
      *(ushort4*)&out_bf[(size_t)n * 256 + l * 4] = o;
    } else {
      a0 += __shfl_xor(a0, 16); a0 += __shfl_xor(a0, 32);
      a1 += __shfl_xor(a1, 16); a1 += __shfl_xor(a1, 32);
      a2 += __shfl_xor(a2, 16); a2 += __shfl_xor(a2, 32);
      a3 += __shfl_xor(a3, 16); a3 += __shfl_xor(a3, 32);
      if (l < 16) {
        float4 b4 = *(const float4*)&bias[l * 4];
        float4 o = make_float4(0.25f * a0 + b4.x, 0.25f * a1 + b4.y,
                               0.25f * a2 + b4.z, 0.25f * a3 + b4.w);
        *(float4*)&out_f[(size_t)n * 64 + l * 4] = o;
      }
    }
  }
}

// ---------------- BatchNorm stats ----------------
__global__ __launch_bounds__(256) void bnstats_bf16_kernel(const unsigned short* __restrict__ x,
                                                           float* __restrict__ sum,
                                                           float* __restrict__ ss, int N) {
  int tid = threadIdx.x;
  int c = (tid & 127) * 2;
  int r = blockIdx.x * 2 + (tid >> 7);
  int stride = gridDim.x * 2;
  float a0 = 0.f, b0 = 0.f, a1 = 0.f, b1 = 0.f;
  for (; r < N; r += stride) {
    unsigned u = *(const unsigned*)&x[(size_t)r * 256 + c];
    float v0 = bflo(u), v1 = bfhi(u);
    a0 += v0; b0 += v0 * v0;
    a1 += v1; b1 += v1 * v1;
  }
  atomicAdd(&sum[c], a0); atomicAdd(&ss[c], b0);
  atomicAdd(&sum[c + 1], a1); atomicAdd(&ss[c + 1], b1);
}

__global__ __launch_bounds__(256) void bnstats_kernel(const float* __restrict__ x,
                                                      float* __restrict__ sum, float* __restrict__ ss,
                                                      int N, int C) {
  int tid = threadIdx.x;
  int f = tid % C;
  int rpb = 256 / C;
  int r = blockIdx.x * rpb + tid / C;
  int stride = gridDim.x * rpb;
  float a = 0.f, b = 0.f;
  for (; r < N; r += stride) {
    float v = x[(size_t)r * C + f];
    a += v;
    b += v * v;
  }
  atomicAdd(&sum[f], a);
  atomicAdd(&ss[f], b);
}

__global__ void bnfinalize_kernel(const float* __restrict__ sum, const float* __restrict__ ss,
                                  const float* __restrict__ gamma, const float* __restrict__ beta,
                                  float* __restrict__ scale, float* __restrict__ shift, int N, int C) {
  int f = threadIdx.x;
  if (f >= C) return;
  float mu = sum[f] / (float)N;
  float var = ss[f] / (float)N - mu * mu;
  float sc = gamma[f] * rsqrtf(var + 1e-5f);
  scale[f] = sc;
  shift[f] = beta[f] - mu * sc;
}

// ---------------- final FC with fused BN2 + ELU ----------------
__global__ __launch_bounds__(256) void fc_kernel(const float* __restrict__ x,
                                                 const float* __restrict__ sc, const float* __restrict__ sh,
                                                 const float* __restrict__ W, const float* __restrict__ b,
                                                 float* __restrict__ out, int N) {
  __shared__ float ws[64 * 86];
  __shared__ float xs[32 * 64];
  int tid = threadIdx.x;
  for (int i = tid; i < 64 * 86; i += 256) ws[i] = W[i];
  int n0 = blockIdx.x * 32;
  for (int i = tid; i < 32 * 64; i += 256) {
    int n = n0 + (i >> 6), c = i & 63;
    float v = (n < N) ? x[(size_t)n * 64 + c] : 0.f;
    v = fmaf(v, sc[c], sh[c]);
    xs[i] = v > 0.f ? v : expm1f(v);
  }
  __syncthreads();
  for (int idx = tid; idx < 32 * 86; idx += 256) {
    int nl = idx / 86, o = idx % 86;
    int n = n0 + nl;
    if (n >= N) continue;
    float acc = b[o];
    const float* xr = &xs[nl * 64];
#pragma unroll 8
    for (int k = 0; k < 64; ++k) acc = fmaf(xr[k], ws[k * 86 + o], acc);
    out[(size_t)n * 86 + o] = acc;
  }
}

extern "C" void kernel_launch(void* const* d_in, const int* in_sizes, int n_in,
                              void* d_out, int out_size, void* d_ws, size_t ws_size,
                              hipStream_t stream) {
  const float* x    = (const float*)d_in[0];
  const int*   ei   = (const int*)d_in[1];
  const float* W1   = (const float*)d_in[2];
  const float* asw1 = (const float*)d_in[3];
  const float* adw1 = (const float*)d_in[4];
  const float* b1   = (const float*)d_in[5];
  const float* W2   = (const float*)d_in[6];
  const float* asw2 = (const float*)d_in[7];
  const float* adw2 = (const float*)d_in[8];
  const float* b2   = (const float*)d_in[9];
  const float* g1   = (const float*)d_in[10];
  const float* be1  = (const float*)d_in[11];
  const float* g2   = (const float*)d_in[12];
  const float* be2  = (const float*)d_in[13];
  const float* pw   = (const float*)d_in[14];
  const float* fcW  = (const float*)d_in[15];
  const float* fcb  = (const float*)d_in[16];

  const int N = in_sizes[0] / 256;
  const int E = in_sizes[1] / 2;
  const int EP = E + N;

  char* ws = (char*)d_ws;
  size_t off = 0;
  auto alloc = [&](size_t bytes) {
    char* p = ws + off;
    off += (bytes + 255) & ~(size_t)255;
    return p;
  };
  unsigned short* h    = (unsigned short*)alloc((size_t)N * 256 * 2);  // bf16 hidden
  unsigned short* outb = (unsigned short*)alloc((size_t)N * 256 * 2);  // bf16 layer-1 out
  float* xm   = (float*)alloc((size_t)N * 64 * 4);                     // fp32 layer-2 out (mean)
  float* as1  = (float*)alloc((size_t)N * 4 * 4);
  float* ad1  = (float*)alloc((size_t)N * 4 * 4);
  float* as2  = (float*)alloc((size_t)N * 4 * 4);
  float* ad2  = (float*)alloc((size_t)N * 4 * 4);
  int* rowptr = (int*)alloc((size_t)(N + 1) * 4);
  int* cnt    = (int*)alloc((size_t)N * 4);
  int* cursor = (int*)alloc((size_t)N * 4);
  int* srcs   = (int*)alloc((size_t)EP * 4);
  int* bsums  = (int*)alloc(1024 * 4);
  unsigned short* Wt1 = (unsigned short*)alloc(65536 * 2);
  unsigned short* Wt2 = (unsigned short*)alloc(65536 * 2);
  float* bstat = (float*)alloc(512 * 4);
  float* bsum = bstat, *bss = bstat + 256;
  float* bsc  = (float*)alloc(256 * 4);
  float* bsh  = (float*)alloc(256 * 4);
  float* bsc2 = (float*)alloc(64 * 4);
  float* bsh2 = (float*)alloc(64 * 4);

  int egrid = (EP + 255) / 256;
  int ngrid4 = (N + 3) / 4;
  int nb = (N + 255) / 256;
  int ggrid = (N + 127) / 128;

  // CSR build + weight conversion
  hipMemsetAsync(cnt, 0, (size_t)N * 4, stream);
  count_kernel<<<egrid, 256, 0, stream>>>(ei, cnt, E, N);
  convw_kernel<<<512, 256, 0, stream>>>(W1, W2, Wt1, Wt2);
  scan1_kernel<<<nb, 256, 0, stream>>>(cnt, bsums, N);
  scan2_kernel<<<1, 256, 0, stream>>>(bsums, nb);
  scan3_kernel<<<nb, 256, 0, stream>>>(cnt, bsums, rowptr, cursor, N);
  fill_kernel<<<egrid, 256, 0, stream>>>(ei, cursor, srcs, E, N);

  // ---- layer 1 (fp32 A converted in-staging) ----
  gemm_kernel<false><<<ggrid, 512, 0, stream>>>(x, Wt1, h, N, nullptr, nullptr, nullptr,
                                                asw1, adw1, as1, ad1);
  agg_kernel<<<ngrid4, 256, 0, stream>>>(h, as1, ad1, rowptr, srcs, b1, outb, nullptr, N, 1);

  hipMemsetAsync(bstat, 0, 512 * 4, stream);
  bnstats_bf16_kernel<<<512, 256, 0, stream>>>(outb, bsum, bss, N);
  bnfinalize_kernel<<<1, 256, 0, stream>>>(bsum, bss, g1, be1, bsc, bsh, N, 256);

  // ---- layer 2 (BN1+PReLU fused into GEMM2 A-staging) ----
  gemm_kernel<true><<<ggrid, 512, 0, stream>>>(outb, Wt2, h, N, bsc, bsh, pw,
                                               asw2, adw2, as2, ad2);
  agg_kernel<<<ngrid4, 256, 0, stream>>>(h, as2, ad2, rowptr, srcs, b2, nullptr, xm, N, 0);

  hipMemsetAsync(bstat, 0, 128 * 4, stream);
  bnstats_kernel<<<512, 256, 0, stream>>>(xm, bstat, bstat + 64, N, 64);
  bnfinalize_kernel<<<1, 64, 0, stream>>>(bstat, bstat + 64, g2, be2, bsc2, bsh2, N, 64);

  // ---- final FC (BN2 + ELU fused) ----
  fc_kernel<<<(N + 31) / 32, 256, 0, stream>>>(xm, bsc2, bsh2, fcW, fcb, (float*)d_out, N);
}

// Round 7
// 512.003 us; speedup vs baseline: 2.0717x; 1.1052x over previous
//
#include <hip/hip_runtime.h>
#include <math.h>

#define LEAKY 0.2f
#define NBMAX 256

typedef __attribute__((ext_vector_type(8))) short short8;   // 8 bf16 (4 VGPRs)
typedef __attribute__((ext_vector_type(4))) float f32x4;    // 4 fp32

__device__ __forceinline__ float leaky02(float z) { return z >= 0.f ? z : LEAKY * z; }
__device__ __forceinline__ unsigned short f2bf(float f) {
  unsigned u = __float_as_uint(f);
  unsigned r = u + 0x7fffu + ((u >> 16) & 1u);   // RNE
  return (unsigned short)(r >> 16);
}
__device__ __forceinline__ float bflo(unsigned u) { return __uint_as_float(u << 16); }
__device__ __forceinline__ float bfhi(unsigned u) { return __uint_as_float(u & 0xffff0000u); }

// ================= bucket-partitioned CSR build (dst-major) =================
// Bucket b = dst>>8 (256 nodes per bucket). Packed pair = (src<<8)|(dst&255).

// Pass A: per-block LDS bucket histogram -> few global atomics
__global__ __launch_bounds__(256) void bktcount_kernel(const int* __restrict__ ei,
                                                       int* __restrict__ bucketCnt,
                                                       int E, int N, int NB) {
  __shared__ int bc[NBMAX];
  for (int i = threadIdx.x; i < NB; i += 256) bc[i] = 0;
  __syncthreads();
  int EP = E + N;
  int chunk = (EP + gridDim.x - 1) / gridDim.x;
  int lo = blockIdx.x * chunk, hi = min(EP, lo + chunk);
  for (int e = lo + threadIdx.x; e < hi; e += 256) {
    int d = (e < E) ? ei[E + e] : (e - E);
    atomicAdd(&bc[d >> 8], 1);
  }
  __syncthreads();
  for (int i = threadIdx.x; i < NB; i += 256)
    if (bc[i]) atomicAdd(&bucketCnt[i], bc[i]);
}

// Pass B: exclusive scan of bucket counts (one block, NB<=256); init cursor
__global__ __launch_bounds__(256) void bktscan_kernel(const int* __restrict__ bucketCnt,
                                                      int* __restrict__ bucketOff,
                                                      int* __restrict__ bucketCur, int NB) {
  int tid = threadIdx.x;
  int lane = tid & 63, wv = tid >> 6;
  int v = (tid < NB) ? bucketCnt[tid] : 0;
  int x = v;
#pragma unroll
  for (int off = 1; off < 64; off <<= 1) {
    int t = __shfl_up(x, off);
    if (lane >= off) x += t;
  }
  __shared__ int ws[4];
  if (lane == 63) ws[wv] = x;
  __syncthreads();
  int woff = 0;
#pragma unroll
  for (int w = 0; w < 4; ++w) if (w < wv) woff += ws[w];
  int incl = x + woff;
  if (tid < NB) {
    bucketOff[tid] = incl - v;
    bucketCur[tid] = incl - v;
  }
  if (tid == NB - 1) bucketOff[NB] = incl;
}

// Pass C: scatter packed pairs into bucket regions; LDS-batched reservations
__global__ __launch_bounds__(256) void bktscatter_kernel(const int* __restrict__ ei,
                                                         int* __restrict__ bucketCur,
                                                         unsigned* __restrict__ pairs,
                                                         int E, int N, int NB) {
  __shared__ int bc[NBMAX];
  __shared__ int bbase[NBMAX];
  for (int i = threadIdx.x; i < NB; i += 256) bc[i] = 0;
  __syncthreads();
  int EP = E + N;
  int chunk = (EP + gridDim.x - 1) / gridDim.x;
  int lo = blockIdx.x * chunk, hi = min(EP, lo + chunk);
  for (int e = lo + threadIdx.x; e < hi; e += 256) {
    int d = (e < E) ? ei[E + e] : (e - E);
    atomicAdd(&bc[d >> 8], 1);
  }
  __syncthreads();
  for (int i = threadIdx.x; i < NB; i += 256) {
    int c = bc[i];
    bbase[i] = c ? atomicAdd(&bucketCur[i], c) : 0;
    bc[i] = 0;   // reuse as local cursor
  }
  __syncthreads();
  for (int e = lo + threadIdx.x; e < hi; e += 256) {
    int s, d;
    if (e < E) { s = ei[e]; d = ei[E + e]; } else { s = e - E; d = s; }
    int b = d >> 8;
    int slot = bbase[b] + atomicAdd(&bc[b], 1);
    pairs[slot] = ((unsigned)s << 8) | (unsigned)(d & 255);
  }
}

// Pass D: per-bucket local CSR in LDS; coalesced rowptr/srcs writes
__global__ __launch_bounds__(256) void bktcsr_kernel(const unsigned* __restrict__ pairs,
                                                     const int* __restrict__ bucketOff,
                                                     int* __restrict__ rowptr,
                                                     int* __restrict__ srcs, int N, int NB) {
  int b = blockIdx.x;
  int tid = threadIdx.x;
  __shared__ int cnt[256], loff[256], cur[256];
  cnt[tid] = 0;
  cur[tid] = 0;
  __syncthreads();
  int p0 = bucketOff[b], p1 = bucketOff[b + 1];
  for (int j = p0 + tid; j < p1; j += 256)
    atomicAdd(&cnt[pairs[j] & 255], 1);
  __syncthreads();
  int v = cnt[tid];
  int lane = tid & 63, wv = tid >> 6;
  int x = v;
#pragma unroll
  for (int off = 1; off < 64; off <<= 1) {
    int t = __shfl_up(x, off);
    if (lane >= off) x += t;
  }
  __shared__ int ws[4];
  if (lane == 63) ws[wv] = x;
  __syncthreads();
  int woff = 0;
#pragma unroll
  for (int w = 0; w < 4; ++w) if (w < wv) woff += ws[w];
  int excl = x + woff - v;
  loff[tid] = excl;
  int node = (b << 8) + tid;
  if (node < N) rowptr[node] = p0 + excl;
  if (b == NB - 1 && tid == 255) rowptr[N] = p1;
  __syncthreads();
  for (int j = p0 + tid; j < p1; j += 256) {
    unsigned pr = pairs[j];
    int ln = pr & 255;
    int slot = p0 + loff[ln] + atomicAdd(&cur[ln], 1);
    srcs[slot] = pr >> 8;
  }
}

// ---------------- weight convert: Wt[c][k] = bf16(W[k][c]) ----------------
__global__ void convw_kernel(const float* __restrict__ W1, const float* __restrict__ W2,
                             unsigned short* __restrict__ Wt1, unsigned short* __restrict__ Wt2) {
  int idx = blockIdx.x * 256 + threadIdx.x;   // 0..131071
  const float* W;
  unsigned short* Wt;
  if (idx < 65536) { W = W1; Wt = Wt1; } else { W = W2; Wt = Wt2; idx -= 65536; }
  int c = idx >> 8, k = idx & 255;
  Wt[c * 256 + k] = f2bf(W[k * 256 + c]);
}

// ---------------- bf16 MFMA GEMM, 128x256 tile, 8 waves (2m x 4n) ----------------
template <bool BF16A>
__global__ __launch_bounds__(512) void gemm_kernel(const void* __restrict__ Av,
                                                   const unsigned short* __restrict__ Wt,
                                                   unsigned short* __restrict__ Hout, int M,
                                                   const float* __restrict__ bnsc,
                                                   const float* __restrict__ bnsh,
                                                   const float* __restrict__ pwp,
                                                   const float* __restrict__ att_s,
                                                   const float* __restrict__ att_d,
                                                   float* __restrict__ as_o,
                                                   float* __restrict__ ad_o) {
  __shared__ unsigned short As[128][40];    // +8 pad
  __shared__ unsigned short Bs[256][40];
  int tid = threadIdx.x;
  int bm = blockIdx.x * 128;
  int l = tid & 63, wv = tid >> 6;
  int wm = wv >> 2, wn = wv & 3;            // 2 x 4 waves; wave tile 64 rows x 64 cols
  int lr = l & 15, lk = l >> 4;
  f32x4 acc[4][4] = {};
  bool hasbn = (bnsc != nullptr);
  float pws = pwp ? pwp[0] : 0.f;

  for (int k0 = 0; k0 < 256; k0 += 32) {
    {
      int row = tid >> 2, kq = (tid & 3) * 8;
      int gr = bm + row;
      if (BF16A) {
        uint4 u = make_uint4(0, 0, 0, 0);
        if (gr < M) u = *(const uint4*)((const unsigned short*)Av + (size_t)gr * 256 + k0 + kq);
        if (hasbn) {
          float4 sc0 = *(const float4*)&bnsc[k0 + kq];
          float4 sh0 = *(const float4*)&bnsh[k0 + kq];
          float4 sc1 = *(const float4*)&bnsc[k0 + kq + 4];
          float4 sh1 = *(const float4*)&bnsh[k0 + kq + 4];
          float v0 = fmaf(bflo(u.x), sc0.x, sh0.x);
          float v1 = fmaf(bfhi(u.x), sc0.y, sh0.y);
          float v2 = fmaf(bflo(u.y), sc0.z, sh0.z);
          float v3 = fmaf(bfhi(u.y), sc0.w, sh0.w);
          float v4 = fmaf(bflo(u.z), sc1.x, sh1.x);
          float v5 = fmaf(bfhi(u.z), sc1.y, sh1.y);
          float v6 = fmaf(bflo(u.w), sc1.z, sh1.z);
          float v7 = fmaf(bfhi(u.w), sc1.w, sh1.w);
          v0 = v0 >= 0.f ? v0 : v0 * pws; v1 = v1 >= 0.f ? v1 : v1 * pws;
          v2 = v2 >= 0.f ? v2 : v2 * pws; v3 = v3 >= 0.f ? v3 : v3 * pws;
          v4 = v4 >= 0.f ? v4 : v4 * pws; v5 = v5 >= 0.f ? v5 : v5 * pws;
          v6 = v6 >= 0.f ? v6 : v6 * pws; v7 = v7 >= 0.f ? v7 : v7 * pws;
          ushort4 o0, o1;
          o0.x = f2bf(v0); o0.y = f2bf(v1); o0.z = f2bf(v2); o0.w = f2bf(v3);
          o1.x = f2bf(v4); o1.y = f2bf(v5); o1.z = f2bf(v6); o1.w = f2bf(v7);
          *(ushort4*)&As[row][kq] = o0;
          *(ushort4*)&As[row][kq + 4] = o1;
        } else {
          *(uint4*)&As[row][kq] = u;
        }
      } else {
        float4 a0 = make_float4(0.f, 0.f, 0.f, 0.f), a1 = a0;
        if (gr < M) {
          a0 = *(const float4*)((const float*)Av + (size_t)gr * 256 + k0 + kq);
          a1 = *(const float4*)((const float*)Av + (size_t)gr * 256 + k0 + kq + 4);
        }
        ushort4 o0, o1;
        o0.x = f2bf(a0.x); o0.y = f2bf(a0.y); o0.z = f2bf(a0.z); o0.w = f2bf(a0.w);
        o1.x = f2bf(a1.x); o1.y = f2bf(a1.y); o1.z = f2bf(a1.z); o1.w = f2bf(a1.w);
        *(ushort4*)&As[row][kq] = o0;
        *(ushort4*)&As[row][kq + 4] = o1;
      }
    }
#pragma unroll
    for (int it = 0; it < 2; ++it) {
      int i = tid + it * 512;
      int c = i >> 2, kq = (i & 3) * 8;
      *(uint4*)&Bs[c][kq] = *(const uint4*)&Wt[(size_t)c * 256 + k0 + kq];
    }
    __syncthreads();
    short8 af[4], bfr[4];
#pragma unroll
    for (int mt = 0; mt < 4; ++mt) af[mt] = *(const short8*)&As[wm * 64 + mt * 16 + lr][lk * 8];
#pragma unroll
    for (int nt = 0; nt < 4; ++nt) bfr[nt] = *(const short8*)&Bs[wn * 64 + nt * 16 + lr][lk * 8];
#pragma unroll
    for (int mt = 0; mt < 4; ++mt)
#pragma unroll
      for (int nt = 0; nt < 4; ++nt)
        acc[mt][nt] = __builtin_amdgcn_mfma_f32_16x16x32_bf16(af[mt], bfr[nt], acc[mt][nt], 0, 0, 0);
    __syncthreads();
  }
  float asv[4], adv[4];
#pragma unroll
  for (int nt = 0; nt < 4; ++nt) {
    int gc = wn * 64 + nt * 16 + lr;
    asv[nt] = att_s[gc];
    adv[nt] = att_d[gc];
  }
#pragma unroll
  for (int mt = 0; mt < 4; ++mt) {
#pragma unroll
    for (int r = 0; r < 4; ++r) {
      int gr = bm + wm * 64 + mt * 16 + lk * 4 + r;
      float ps = acc[mt][0][r] * asv[0] + acc[mt][1][r] * asv[1] +
                 acc[mt][2][r] * asv[2] + acc[mt][3][r] * asv[3];
      float pd = acc[mt][0][r] * adv[0] + acc[mt][1][r] * adv[1] +
                 acc[mt][2][r] * adv[2] + acc[mt][3][r] * adv[3];
#pragma unroll
      for (int off = 1; off < 16; off <<= 1) {
        ps += __shfl_xor(ps, off);
        pd += __shfl_xor(pd, off);
      }
      if (lr == 0 && gr < M) {
        as_o[gr * 4 + wn] = ps;
        ad_o[gr * 4 + wn] = pd;
      }
      if (gr < M) {
#pragma unroll
        for (int nt = 0; nt < 4; ++nt)
          Hout[(size_t)gr * 256 + wn * 64 + nt * 16 + lr] = f2bf(acc[mt][nt][r]);
      }
    }
  }
}

// ---------------- GAT aggregation: wave per node; uint4 gather, 2 edges/iter ----------------
__global__ __launch_bounds__(256) void agg_kernel(const unsigned short* __restrict__ h,
                                                  const float* __restrict__ as_,
                                                  const float* __restrict__ ad_,
                                                  const int* __restrict__ rowptr,
                                                  const int* __restrict__ srcs,
                                                  const float* __restrict__ bias,
                                                  unsigned short* __restrict__ out_bf,
                                                  float* __restrict__ out_f,
                                                  int N, int concat) {
  int l = threadIdx.x & 63;
  int n = blockIdx.x * 4 + (threadIdx.x >> 6);
  if (n >= N) return;
  int e0 = rowptr[n], e1 = rowptr[n + 1];
  int deg = e1 - e0;
  int hh = l >> 4, le = l & 15;
  float adh = ad_[n * 4 + hh];

  if (deg <= 64) {
    int sidx[4];
    float lg[4];
#pragma unroll
    for (int t = 0; t < 4; ++t) {
      int j = e0 + le + 16 * t;
      if (j < e1) {
        int s = srcs[j];
        sidx[t] = s;
        lg[t] = leaky02(as_[s * 4 + hh] + adh);
      } else {
        sidx[t] = 0;
        lg[t] = -1e30f;
      }
    }
    float mx = fmaxf(fmaxf(lg[0], lg[1]), fmaxf(lg[2], lg[3]));
#pragma unroll
    for (int off = 1; off < 16; off <<= 1) mx = fmaxf(mx, __shfl_xor(mx, off));
    float ex[4];
    float sm = 0.f;
#pragma unroll
    for (int t = 0; t < 4; ++t) {
      ex[t] = (lg[t] > -1e29f) ? __expf(lg[t] - mx) : 0.f;
      sm += ex[t];
    }
#pragma unroll
    for (int off = 1; off < 16; off <<= 1) sm += __shfl_xor(sm, off);
    float inv = 1.f / (sm + 1e-16f);

    int p = l >> 5, m = l & 31;
    int hb = m >> 3;
    float invb = __shfl(inv, hb << 4);
    float a[8] = {0.f, 0.f, 0.f, 0.f, 0.f, 0.f, 0.f, 0.f};
#pragma unroll
    for (int t = 0; t < 4; ++t) {
      int base = e0 + 16 * t;
      if (base >= e1) break;
      int cntc = min(16, e1 - base);
      int npr = (cntc + 1) >> 1;
      for (int pr = 0; pr < npr; ++pr) {
        int q = 2 * pr + p;
        int s = __shfl(sidx[t], q);
        float al = __shfl(ex[t], q + (hb << 4)) * invb;
        uint4 hv = *(const uint4*)&h[(size_t)s * 256 + m * 8];
        a[0] = fmaf(bflo(hv.x), al, a[0]);
        a[1] = fmaf(bfhi(hv.x), al, a[1]);
        a[2] = fmaf(bflo(hv.y), al, a[2]);
        a[3] = fmaf(bfhi(hv.y), al, a[3]);
        a[4] = fmaf(bflo(hv.z), al, a[4]);
        a[5] = fmaf(bfhi(hv.z), al, a[5]);
        a[6] = fmaf(bflo(hv.w), al, a[6]);
        a[7] = fmaf(bfhi(hv.w), al, a[7]);
      }
    }
#pragma unroll
    for (int i = 0; i < 8; ++i) a[i] += __shfl_xor(a[i], 32);
    if (concat) {
      if (l < 32) {
        float4 b0 = *(const float4*)&bias[m * 8];
        float4 b1 = *(const float4*)&bias[m * 8 + 4];
        ushort4 o0, o1;
        o0.x = f2bf(a[0] + b0.x); o0.y = f2bf(a[1] + b0.y);
        o0.z = f2bf(a[2] + b0.z); o0.w = f2bf(a[3] + b0.w);
        o1.x = f2bf(a[4] + b1.x); o1.y = f2bf(a[5] + b1.y);
        o1.z = f2bf(a[6] + b1.z); o1.w = f2bf(a[7] + b1.w);
        *(ushort4*)&out_bf[(size_t)n * 256 + m * 8] = o0;
        *(ushort4*)&out_bf[(size_t)n * 256 + m * 8 + 4] = o1;
      }
    } else {
#pragma unroll
      for (int i = 0; i < 8; ++i) {
        a[i] += __shfl_xor(a[i], 8);
        a[i] += __shfl_xor(a[i], 16);
      }
      if (l < 8) {
        float4 b0 = *(const float4*)&bias[m * 8];
        float4 b1 = *(const float4*)&bias[m * 8 + 4];
        float4 o0 = make_float4(0.25f * a[0] + b0.x, 0.25f * a[1] + b0.y,
                                0.25f * a[2] + b0.z, 0.25f * a[3] + b0.w);
        float4 o1 = make_float4(0.25f * a[4] + b1.x, 0.25f * a[5] + b1.y,
                                0.25f * a[6] + b1.z, 0.25f * a[7] + b1.w);
        *(float4*)&out_f[(size_t)n * 64 + m * 8] = o0;
        *(float4*)&out_f[(size_t)n * 64 + m * 8 + 4] = o1;
      }
    }
  } else {
    float ad4[4] = {ad_[n * 4], ad_[n * 4 + 1], ad_[n * 4 + 2], ad_[n * 4 + 3]};
    float mx[4] = {-1e30f, -1e30f, -1e30f, -1e30f};
    for (int j = e0 + l; j < e1; j += 64) {
      int s = srcs[j];
      float4 av = *(const float4*)&as_[s * 4];
      mx[0] = fmaxf(mx[0], leaky02(av.x + ad4[0]));
      mx[1] = fmaxf(mx[1], leaky02(av.y + ad4[1]));
      mx[2] = fmaxf(mx[2], leaky02(av.z + ad4[2]));
      mx[3] = fmaxf(mx[3], leaky02(av.w + ad4[3]));
    }
#pragma unroll
    for (int off = 32; off; off >>= 1) {
      mx[0] = fmaxf(mx[0], __shfl_xor(mx[0], off));
      mx[1] = fmaxf(mx[1], __shfl_xor(mx[1], off));
      mx[2] = fmaxf(mx[2], __shfl_xor(mx[2], off));
      mx[3] = fmaxf(mx[3], __shfl_xor(mx[3], off));
    }
    float sm[4] = {0.f, 0.f, 0.f, 0.f};
    for (int j = e0 + l; j < e1; j += 64) {
      int s = srcs[j];
      float4 av = *(const float4*)&as_[s * 4];
      sm[0] += __expf(leaky02(av.x + ad4[0]) - mx[0]);
      sm[1] += __expf(leaky02(av.y + ad4[1]) - mx[1]);
      sm[2] += __expf(leaky02(av.z + ad4[2]) - mx[2]);
      sm[3] += __expf(leaky02(av.w + ad4[3]) - mx[3]);
    }
#pragma unroll
    for (int off = 32; off; off >>= 1) {
      sm[0] += __shfl_xor(sm[0], off);
      sm[1] += __shfl_xor(sm[1], off);
      sm[2] += __shfl_xor(sm[2], off);
      sm[3] += __shfl_xor(sm[3], off);
    }
    float mh = hh == 0 ? mx[0] : hh == 1 ? mx[1] : hh == 2 ? mx[2] : mx[3];
    float sh = hh == 0 ? sm[0] : hh == 1 ? sm[1] : hh == 2 ? sm[2] : sm[3];
    float inv = 1.f / (sh + 1e-16f);
    float a0 = 0.f, a1 = 0.f, a2 = 0.f, a3 = 0.f;
    for (int j = e0; j < e1; ++j) {
      int s = srcs[j];
      float al = __expf(leaky02(as_[s * 4 + hh] + adh) - mh) * inv;
      uint2 hv = *(const uint2*)&h[(size_t)s * 256 + l * 4];
      a0 = fmaf(bflo(hv.x), al, a0); a1 = fmaf(bfhi(hv.x), al, a1);
      a2 = fmaf(bflo(hv.y), al, a2); a3 = fmaf(bfhi(hv.y), al, a3);
    }
    if (concat) {
      float4 b4 = *(const float4*)&bias[l * 4];
      ushort4 o;
      o.x = f2bf(a0 + b4.x); o.y = f2bf(a1 + b4.y);
      o.z = f2bf(a2 + b4.z); o.w = f2bf(a3 + b4.w);
      *(ushort4*)&out_bf[(size_t)n * 256 + l * 4] = o;
    } else {
      a0 += __shfl_xor(a0, 16); a0 += __shfl_xor(a0, 32);
      a1 += __shfl_xor(a1, 16); a1 += __shfl_xor(a1, 32);
      a2 += __shfl_xor(a2, 16); a2 += __shfl_xor(a2, 32);
      a3 += __shfl_xor(a3, 16); a3 += __shfl_xor(a3, 32);
      if (l < 16) {
        float4 b4 = *(const float4*)&bias[l * 4];
        float4 o = make_float4(0.25f * a0 + b4.x, 0.25f * a1 + b4.y,
                               0.25f * a2 + b4.z, 0.25f * a3 + b4.w);
        *(float4*)&out_f[(size_t)n * 64 + l * 4] = o;
      }
    }
  }
}

// ---------------- BatchNorm stats ----------------
__global__ __launch_bounds__(256) void bnstats_bf16_kernel(const unsigned short* __restrict__ x,
                                                           float* __restrict__ sum,
                                                           float* __restrict__ ss, int N) {
  int tid = threadIdx.x;
  int c = (tid & 127) * 2;
  int r = blockIdx.x * 2 + (tid >> 7);
  int stride = gridDim.x * 2;
  float a0 = 0.f, b0 = 0.f, a1 = 0.f, b1 = 0.f;
  for (; r < N; r += stride) {
    unsigned u = *(const unsigned*)&x[(size_t)r * 256 + c];
    float v0 = bflo(u), v1 = bfhi(u);
    a0 += v0; b0 += v0 * v0;
    a1 += v1; b1 += v1 * v1;
  }
  atomicAdd(&sum[c], a0); atomicAdd(&ss[c], b0);
  atomicAdd(&sum[c + 1], a1); atomicAdd(&ss[c + 1], b1);
}

__global__ __launch_bounds__(256) void bnstats_kernel(const float* __restrict__ x,
                                                      float* __restrict__ sum, float* __restrict__ ss,
                                                      int N, int C) {
  int tid = threadIdx.x;
  int f = tid % C;
  int rpb = 256 / C;
  int r = blockIdx.x * rpb + tid / C;
  int stride = gridDim.x * rpb;
  float a = 0.f, b = 0.f;
  for (; r < N; r += stride) {
    float v = x[(size_t)r * C + f];
    a += v;
    b += v * v;
  }
  atomicAdd(&sum[f], a);
  atomicAdd(&ss[f], b);
}

__global__ void bnfinalize_kernel(const float* __restrict__ sum, const float* __restrict__ ss,
                                  const float* __restrict__ gamma, const float* __restrict__ beta,
                                  float* __restrict__ scale, float* __restrict__ shift, int N, int C) {
  int f = threadIdx.x;
  if (f >= C) return;
  float mu = sum[f] / (float)N;
  float var = ss[f] / (float)N - mu * mu;
  float sc = gamma[f] * rsqrtf(var + 1e-5f);
  scale[f] = sc;
  shift[f] = beta[f] - mu * sc;
}

// ---------------- final FC with fused BN2 + ELU ----------------
__global__ __launch_bounds__(256) void fc_kernel(const float* __restrict__ x,
                                                 const float* __restrict__ sc, const float* __restrict__ sh,
                                                 const float* __restrict__ W, const float* __restrict__ b,
                                                 float* __restrict__ out, int N) {
  __shared__ float ws[64 * 86];
  __shared__ float xs[32 * 64];
  int tid = threadIdx.x;
  for (int i = tid; i < 64 * 86; i += 256) ws[i] = W[i];
  int n0 = blockIdx.x * 32;
  for (int i = tid; i < 32 * 64; i += 256) {
    int n = n0 + (i >> 6), c = i & 63;
    float v = (n < N) ? x[(size_t)n * 64 + c] : 0.f;
    v = fmaf(v, sc[c], sh[c]);
    xs[i] = v > 0.f ? v : expm1f(v);
  }
  __syncthreads();
  for (int idx = tid; idx < 32 * 86; idx += 256) {
    int nl = idx / 86, o = idx % 86;
    int n = n0 + nl;
    if (n >= N) continue;
    float acc = b[o];
    const float* xr = &xs[nl * 64];
#pragma unroll 8
    for (int k = 0; k < 64; ++k) acc = fmaf(xr[k], ws[k * 86 + o], acc);
    out[(size_t)n * 86 + o] = acc;
  }
}

extern "C" void kernel_launch(void* const* d_in, const int* in_sizes, int n_in,
                              void* d_out, int out_size, void* d_ws, size_t ws_size,
                              hipStream_t stream) {
  const float* x    = (const float*)d_in[0];
  const int*   ei   = (const int*)d_in[1];
  const float* W1   = (const float*)d_in[2];
  const float* asw1 = (const float*)d_in[3];
  const float* adw1 = (const float*)d_in[4];
  const float* b1   = (const float*)d_in[5];
  const float* W2   = (const float*)d_in[6];
  const float* asw2 = (const float*)d_in[7];
  const float* adw2 = (const float*)d_in[8];
  const float* b2   = (const float*)d_in[9];
  const float* g1   = (const float*)d_in[10];
  const float* be1  = (const float*)d_in[11];
  const float* g2   = (const float*)d_in[12];
  const float* be2  = (const float*)d_in[13];
  const float* pw   = (const float*)d_in[14];
  const float* fcW  = (const float*)d_in[15];
  const float* fcb  = (const float*)d_in[16];

  const int N = in_sizes[0] / 256;
  const int E = in_sizes[1] / 2;
  const int EP = E + N;
  const int NB = (N + 255) / 256;

  char* ws = (char*)d_ws;
  size_t off = 0;
  auto alloc = [&](size_t bytes) {
    char* p = ws + off;
    off += (bytes + 255) & ~(size_t)255;
    return p;
  };
  unsigned short* h    = (unsigned short*)alloc((size_t)N * 256 * 2);  // bf16 hidden
  unsigned short* outb = (unsigned short*)alloc((size_t)N * 256 * 2);  // bf16 layer-1 out
  float* xm   = (float*)alloc((size_t)N * 64 * 4);                     // fp32 layer-2 out (mean)
  float* as1  = (float*)alloc((size_t)N * 4 * 4);
  float* ad1  = (float*)alloc((size_t)N * 4 * 4);
  float* as2  = (float*)alloc((size_t)N * 4 * 4);
  float* ad2  = (float*)alloc((size_t)N * 4 * 4);
  int* rowptr = (int*)alloc((size_t)(N + 1) * 4);
  int* srcs   = (int*)alloc((size_t)EP * 4);
  unsigned* pairs = (unsigned*)alloc((size_t)EP * 4);
  int* bucketCnt = (int*)alloc((NBMAX + 1) * 4);
  int* bucketOff = (int*)alloc((NBMAX + 1) * 4);
  int* bucketCur = (int*)alloc((NBMAX + 1) * 4);
  unsigned short* Wt1 = (unsigned short*)alloc(65536 * 2);
  unsigned short* Wt2 = (unsigned short*)alloc(65536 * 2);
  float* bstat = (float*)alloc(512 * 4);
  float* bsum = bstat, *bss = bstat + 256;
  float* bsc  = (float*)alloc(256 * 4);
  float* bsh  = (float*)alloc(256 * 4);
  float* bsc2 = (float*)alloc(64 * 4);
  float* bsh2 = (float*)alloc(64 * 4);

  int ngrid4 = (N + 3) / 4;
  int ggrid = (N + 127) / 128;

  // CSR build (bucket-partitioned) + weight conversion
  hipMemsetAsync(bucketCnt, 0, (NBMAX + 1) * 4, stream);
  bktcount_kernel<<<256, 256, 0, stream>>>(ei, bucketCnt, E, N, NB);
  convw_kernel<<<512, 256, 0, stream>>>(W1, W2, Wt1, Wt2);
  bktscan_kernel<<<1, 256, 0, stream>>>(bucketCnt, bucketOff, bucketCur, NB);
  bktscatter_kernel<<<256, 256, 0, stream>>>(ei, bucketCur, pairs, E, N, NB);
  bktcsr_kernel<<<NB, 256, 0, stream>>>(pairs, bucketOff, rowptr, srcs, N, NB);

  // ---- layer 1 (fp32 A converted in-staging) ----
  gemm_kernel<false><<<ggrid, 512, 0, stream>>>(x, Wt1, h, N, nullptr, nullptr, nullptr,
                                                asw1, adw1, as1, ad1);
  agg_kernel<<<ngrid4, 256, 0, stream>>>(h, as1, ad1, rowptr, srcs, b1, outb, nullptr, N, 1);

  hipMemsetAsync(bstat, 0, 512 * 4, stream);
  bnstats_bf16_kernel<<<512, 256, 0, stream>>>(outb, bsum, bss, N);
  bnfinalize_kernel<<<1, 256, 0, stream>>>(bsum, bss, g1, be1, bsc, bsh, N, 256);

  // ---- layer 2 (BN1+PReLU fused into GEMM2 A-staging) ----
  gemm_kernel<true><<<ggrid, 512, 0, stream>>>(outb, Wt2, h, N, bsc, bsh, pw,
                                               asw2, adw2, as2, ad2);
  agg_kernel<<<ngrid4, 256, 0, stream>>>(h, as2, ad2, rowptr, srcs, b2, nullptr, xm, N, 0);

  hipMemsetAsync(bstat, 0, 128 * 4, stream);
  bnstats_kernel<<<512, 256, 0, stream>>>(xm, bstat, bstat + 64, N, 64);
  bnfinalize_kernel<<<1, 64, 0, stream>>>(bstat, bstat + 64, g2, be2, bsc2, bsh2, N, 64);

  // ---- final FC (BN2 + ELU fused) ----
  fc_kernel<<<(N + 31) / 32, 256, 0, stream>>>(xm, bsc2, bsh2, fcW, fcb, (float*)d_out, N);
}